// Round 2
// baseline (566.622 us; speedup 1.0000x reference)
//
#include <hip/hip_runtime.h>
#include <hip/hip_bf16.h>

// Transformer block fwd: x:[2,2048,1024] fp32. bf16 MFMA GEMMs + flash attn.
// E=1024 H=16 D=64 HID=4096, causal, exact GELU, LN eps=1e-6.

#define E_    1024
#define TE_   3072
#define S_    2048
#define B_    2
#define H_    16
#define MROWS 4096   // B*S

typedef __attribute__((ext_vector_type(8))) short bf16x8;
typedef __attribute__((ext_vector_type(4))) short short4v;
typedef __attribute__((ext_vector_type(4))) float f32x4;

__device__ __forceinline__ short f2bf(float f) {
  union { float f; unsigned u; } v; v.f = f;
  unsigned r = v.u + 0x7fffu + ((v.u >> 16) & 1u);  // RNE
  return (short)(r >> 16);
}
__device__ __forceinline__ float bf2f(short s) {
  union { unsigned u; float f; } v; v.u = ((unsigned)(unsigned short)s) << 16;
  return v.f;
}
__device__ __forceinline__ void gload_lds16(const void* g, void* l) {
  __builtin_amdgcn_global_load_lds(
      (const __attribute__((address_space(1))) unsigned int*)g,
      (__attribute__((address_space(3))) unsigned int*)l, 16, 0, 0);
}
__device__ __forceinline__ float gelu_f(float v) {
  return 0.5f * v * (1.0f + erff(v * 0.70710678118654752f));
}

// ---------------- fp32 -> bf16 weight convert ----------------
__global__ __launch_bounds__(256) void k_cvt(const float* __restrict__ in,
                                             short* __restrict__ out, int n4) {
  int i = blockIdx.x * 256 + threadIdx.x;
  if (i >= n4) return;
  float4 v = ((const float4*)in)[i];
  short4v o = { f2bf(v.x), f2bf(v.y), f2bf(v.z), f2bf(v.w) };
  ((short4v*)out)[i] = o;
}

// ---------------- LayerNorm fp32 -> bf16 ----------------
__global__ __launch_bounds__(256) void k_ln(const float* __restrict__ x,
                                            const float* __restrict__ w,
                                            const float* __restrict__ b,
                                            short* __restrict__ out) {
  int row = blockIdx.x;
  int tid = threadIdx.x;
  float4 v = ((const float4*)(x + (size_t)row * E_))[tid];
  float s  = v.x + v.y + v.z + v.w;
  float s2 = v.x*v.x + v.y*v.y + v.z*v.z + v.w*v.w;
  #pragma unroll
  for (int d = 1; d < 64; d <<= 1) { s += __shfl_xor(s, d); s2 += __shfl_xor(s2, d); }
  __shared__ float rs[4], rq[4];
  int wv = tid >> 6;
  if ((tid & 63) == 0) { rs[wv] = s; rq[wv] = s2; }
  __syncthreads();
  s  = rs[0] + rs[1] + rs[2] + rs[3];
  s2 = rq[0] + rq[1] + rq[2] + rq[3];
  float mu  = s * (1.0f / E_);
  float var = fmaxf(s2 * (1.0f / E_) - mu * mu, 0.0f);
  float inv = rsqrtf(var + 1e-6f);
  float4 wv4 = ((const float4*)w)[tid];
  float4 bv4 = ((const float4*)b)[tid];
  short4v o = { f2bf((v.x - mu) * inv * wv4.x + bv4.x),
                f2bf((v.y - mu) * inv * wv4.y + bv4.y),
                f2bf((v.z - mu) * inv * wv4.z + bv4.z),
                f2bf((v.w - mu) * inv * wv4.w + bv4.w) };
  ((short4v*)(out + (size_t)row * E_))[tid] = o;
}

// ---------------- bf16 GEMM: out[m,n] = sum_k A[m,k]*W[n,k] (+epilogue) ----
// EPI: 0 = +bias -> bf16 ; 1 = +bias+res -> fp32 ; 2 = +bias, gelu -> bf16
template <int EPI>
__global__ __launch_bounds__(256) void k_gemm(const short* __restrict__ A,
                                              const short* __restrict__ W,
                                              const float* __restrict__ bias,
                                              const float* __restrict__ res,
                                              void* __restrict__ outv,
                                              int M, int N, int K) {
  __shared__ short As[128 * 32];
  __shared__ short Ws[128 * 32];
  int tid  = threadIdx.x;
  int lane = tid & 63, wave = tid >> 6;
  int wm = wave >> 1, wn = wave & 1;
  int m0 = blockIdx.y * 128, n0 = blockIdx.x * 128;
  int fr = lane & 15, fq = lane >> 4, fk = fq * 8;

  f32x4 acc[4][4];
  #pragma unroll
  for (int i = 0; i < 4; ++i)
    #pragma unroll
    for (int j = 0; j < 4; ++j) acc[i][j] = (f32x4){0.f, 0.f, 0.f, 0.f};

  int sr = tid >> 2;           // staging: flat = tid*8 -> row=tid/4, col=(tid%4)*8
  int sc = (tid & 3) * 8;
  const short* Arow  = A + (size_t)(m0 + sr) * K + sc;
  const short* Wrow  = W + (size_t)(n0 + sr) * K + sc;
  const short* Arow2 = A + (size_t)(m0 + 64 + sr) * K + sc;
  const short* Wrow2 = W + (size_t)(n0 + 64 + sr) * K + sc;
  short* Asl = As + tid * 8;
  short* Wsl = Ws + tid * 8;

  for (int k0 = 0; k0 < K; k0 += 32) {
    __syncthreads();
    gload_lds16(Arow  + k0, Asl);
    gload_lds16(Wrow  + k0, Wsl);
    gload_lds16(Arow2 + k0, Asl + 2048);
    gload_lds16(Wrow2 + k0, Wsl + 2048);
    __syncthreads();
    bf16x8 af[4], bfr[4];
    #pragma unroll
    for (int i = 0; i < 4; ++i) {
      af[i]  = *(const bf16x8*)(As + (wm * 64 + i * 16 + fr) * 32 + fk);
      bfr[i] = *(const bf16x8*)(Ws + (wn * 64 + i * 16 + fr) * 32 + fk);
    }
    #pragma unroll
    for (int mi = 0; mi < 4; ++mi)
      #pragma unroll
      for (int ni = 0; ni < 4; ++ni)
        acc[mi][ni] = __builtin_amdgcn_mfma_f32_16x16x32_bf16(af[mi], bfr[ni],
                                                              acc[mi][ni], 0, 0, 0);
  }

  #pragma unroll
  for (int mi = 0; mi < 4; ++mi) {
    #pragma unroll
    for (int ni = 0; ni < 4; ++ni) {
      int gm0 = m0 + wm * 64 + mi * 16 + fq * 4;
      int gn  = n0 + wn * 64 + ni * 16 + fr;
      float bv = bias[gn];
      #pragma unroll
      for (int j = 0; j < 4; ++j) {
        size_t idx = (size_t)(gm0 + j) * N + gn;
        float v = acc[mi][ni][j] + bv;
        if (EPI == 0)      ((short*)outv)[idx] = f2bf(v);
        else if (EPI == 1) ((float*)outv)[idx] = v + res[idx];
        else               ((short*)outv)[idx] = f2bf(gelu_f(v));
      }
    }
  }
}

// ---------------- causal flash attention ----------------
// qkv: [B*S][3072] bf16 (Q|K|V, head-major inside). out: [B*S][1024] bf16.
// Block: 4 waves; wave w owns 16 q-rows; Q-tile=64, KV-tile=32.
__global__ __launch_bounds__(256) void k_attn(const short* __restrict__ qkv,
                                              short* __restrict__ out) {
  __shared__ short Kt[32 * 72];    // [key][dim], +8 pad
  __shared__ short Vt[64 * 40];    // transposed: [dim][key], +8 pad
  __shared__ short Pb[4 * 512];    // per-wave P tile 16x32
  int tid  = threadIdx.x;
  int lane = tid & 63, w = tid >> 6;
  int q0 = blockIdx.x * 64;
  int bh = blockIdx.y;
  int b = bh >> 4, h = bh & 15;
  int fr = lane & 15, fq = lane >> 4, fk = fq * 8;

  // Q fragments, prescaled by 1/sqrt(D)=0.125
  int qrow = q0 + w * 16 + fr;
  const short* qp = qkv + (size_t)(b * S_ + qrow) * TE_ + h * 64;
  bf16x8 qa[2];
  #pragma unroll
  for (int c = 0; c < 2; ++c) {
    bf16x8 t = *(const bf16x8*)(qp + c * 32 + fk);
    #pragma unroll
    for (int j = 0; j < 8; ++j) t[j] = f2bf(bf2f(t[j]) * 0.125f);
    qa[c] = t;
  }

  float m_r[4] = {-__builtin_inff(), -__builtin_inff(),
                  -__builtin_inff(), -__builtin_inff()};
  float l_r[4] = {0.f, 0.f, 0.f, 0.f};
  f32x4 o[4];
  #pragma unroll
  for (int c = 0; c < 4; ++c) o[c] = (f32x4){0.f, 0.f, 0.f, 0.f};

  short* Pw = Pb + w * 512;
  int skey = tid >> 3;            // staging: key 0..31
  int sd   = (tid & 7) * 8;       // dim 0..56
  int qmax_w = q0 + w * 16 + 15;
  int kv_end = q0 + 64;

  for (int kv = 0; kv < kv_end; kv += 32) {
    __syncthreads();
    const short* kp = qkv + (size_t)(b * S_ + kv + skey) * TE_ + E_ + h * 64 + sd;
    *(bf16x8*)(Kt + skey * 72 + sd) = *(const bf16x8*)kp;
    const short* vp = qkv + (size_t)(b * S_ + kv + skey) * TE_ + 2 * E_ + h * 64 + sd;
    bf16x8 vv = *(const bf16x8*)vp;
    #pragma unroll
    for (int j = 0; j < 8; ++j) Vt[(sd + j) * 40 + skey] = vv[j];
    __syncthreads();
    if (kv > qmax_w) continue;     // wave-uniform; barriers stay consistent

    // S = (Q*scale) @ K^T  (16q x 32keys, two 16-key groups)
    f32x4 s[2];
    #pragma unroll
    for (int g = 0; g < 2; ++g) {
      bf16x8 k0f = *(const bf16x8*)(Kt + (g * 16 + fr) * 72 + fk);
      bf16x8 k1f = *(const bf16x8*)(Kt + (g * 16 + fr) * 72 + 32 + fk);
      f32x4 t = (f32x4){0.f, 0.f, 0.f, 0.f};
      t = __builtin_amdgcn_mfma_f32_16x16x32_bf16(qa[0], k0f, t, 0, 0, 0);
      t = __builtin_amdgcn_mfma_f32_16x16x32_bf16(qa[1], k1f, t, 0, 0, 0);
      s[g] = t;
    }

    int qrow_base = q0 + w * 16 + fq * 4;
    #pragma unroll
    for (int j = 0; j < 4; ++j) {
      int gq = qrow_base + j;
      #pragma unroll
      for (int g = 0; g < 2; ++g) {
        int key = kv + g * 16 + fr;
        if (key > gq) s[g][j] = -__builtin_inff();
      }
      float mt = fmaxf(s[0][j], s[1][j]);
      mt = fmaxf(mt, __shfl_xor(mt, 1));
      mt = fmaxf(mt, __shfl_xor(mt, 2));
      mt = fmaxf(mt, __shfl_xor(mt, 4));
      mt = fmaxf(mt, __shfl_xor(mt, 8));
      float mn = fmaxf(m_r[j], mt);
      float al = __expf(m_r[j] - mn);
      float p0 = __expf(s[0][j] - mn);
      float p1 = __expf(s[1][j] - mn);
      float rsum = p0 + p1;
      rsum += __shfl_xor(rsum, 1);
      rsum += __shfl_xor(rsum, 2);
      rsum += __shfl_xor(rsum, 4);
      rsum += __shfl_xor(rsum, 8);
      l_r[j] = l_r[j] * al + rsum;
      m_r[j] = mn;
      #pragma unroll
      for (int c = 0; c < 4; ++c) o[c][j] *= al;
      Pw[(fq * 4 + j) * 32 + fr]      = f2bf(p0);
      Pw[(fq * 4 + j) * 32 + 16 + fr] = f2bf(p1);
    }

    // O += P @ V   (P: 16x32 A-frag from LDS; V^T rows give B-frags)
    bf16x8 pa = *(const bf16x8*)(Pw + fr * 32 + fk);
    #pragma unroll
    for (int c = 0; c < 4; ++c) {
      bf16x8 vb = *(const bf16x8*)(Vt + (c * 16 + fr) * 40 + fk);
      o[c] = __builtin_amdgcn_mfma_f32_16x16x32_bf16(pa, vb, o[c], 0, 0, 0);
    }
  }

  #pragma unroll
  for (int c = 0; c < 4; ++c) {
    #pragma unroll
    for (int j = 0; j < 4; ++j) {
      int gq = q0 + w * 16 + fq * 4 + j;
      float v = o[c][j] / l_r[j];
      out[(size_t)(b * S_ + gq) * E_ + h * 64 + c * 16 + fr] = f2bf(v);
    }
  }
}

// ---------------- launch ----------------
extern "C" void kernel_launch(void* const* d_in, const int* in_sizes, int n_in,
                              void* d_out, int out_size, void* d_ws, size_t ws_size,
                              hipStream_t stream) {
  const float* x      = (const float*)d_in[0];
  const float* ln1_w  = (const float*)d_in[1];
  const float* ln1_b  = (const float*)d_in[2];
  const float* qkv_w  = (const float*)d_in[3];
  const float* qkv_b  = (const float*)d_in[4];
  const float* proj_w = (const float*)d_in[5];
  const float* proj_b = (const float*)d_in[6];
  const float* ln2_w  = (const float*)d_in[7];
  const float* ln2_b  = (const float*)d_in[8];
  const float* fc1_w  = (const float*)d_in[9];
  const float* fc1_b  = (const float*)d_in[10];
  const float* fc2_w  = (const float*)d_in[11];
  const float* fc2_b  = (const float*)d_in[12];
  float* out = (float*)d_out;

  char* ws = (char*)d_ws;
  // Timeline-overlapped layout (80 MB total):
  short* xn1    = (short*)(ws + 0);              // 8 MB  [4096][1024] (dead after qkv gemm)
  short* qkvb   = (short*)(ws + (8u  << 20));    // 24 MB [4096][3072] (dead after attn)
  short* gelu_o = (short*)(ws + 0);              // 32 MB [4096][4096] (reuses xn1+qkvb)
  short* attn_o = (short*)(ws + (32u << 20));    // 8 MB  (dead after proj gemm)
  short* h_ln2  = (short*)(ws + (32u << 20));    // 8 MB  (reuses attn_o)
  float* x_res  = (float*)(ws + (40u << 20));    // 16 MB fp32
  short* w_qkv  = (short*)(ws + (56u << 20));    // 6 MB
  short* w_proj = (short*)(ws + (62u << 20));    // 2 MB
  short* w_fc1  = (short*)(ws + (64u << 20));    // 8 MB
  short* w_fc2  = (short*)(ws + (72u << 20));    // 8 MB

  k_cvt<<<3072, 256, 0, stream>>>(qkv_w, w_qkv, 786432);
  k_cvt<<<1024, 256, 0, stream>>>(proj_w, w_proj, 262144);
  k_cvt<<<4096, 256, 0, stream>>>(fc1_w, w_fc1, 1048576);
  k_cvt<<<4096, 256, 0, stream>>>(fc2_w, w_fc2, 1048576);

  k_ln<<<MROWS, 256, 0, stream>>>(x, ln1_w, ln1_b, xn1);
  k_gemm<0><<<dim3(24, 32), 256, 0, stream>>>(xn1, w_qkv, qkv_b, nullptr, qkvb,
                                              MROWS, TE_, E_);
  k_attn<<<dim3(S_ / 64, B_ * H_), 256, 0, stream>>>(qkvb, attn_o);
  k_gemm<1><<<dim3(8, 32), 256, 0, stream>>>(attn_o, w_proj, proj_b, x, x_res,
                                             MROWS, E_, E_);
  k_ln<<<MROWS, 256, 0, stream>>>(x_res, ln2_w, ln2_b, h_ln2);
  k_gemm<2><<<dim3(32, 32), 256, 0, stream>>>(h_ln2, w_fc1, fc1_b, nullptr, gelu_o,
                                              MROWS, 4096, E_);
  k_gemm<1><<<dim3(8, 32), 256, 0, stream>>>(gelu_o, w_fc2, fc2_b, x_res, out,
                                             MROWS, E_, 4096);
}

// Round 4
// 444.058 us; speedup vs baseline: 1.2760x; 1.2760x over previous
//
#include <hip/hip_runtime.h>
#include <hip/hip_bf16.h>

// Transformer block fwd: x:[2,2048,1024] fp32. bf16 MFMA GEMMs + flash attn.
// E=1024 H=16 D=64 HID=4096, causal, exact GELU, LN eps=1e-6.

#define E_    1024
#define TE_   3072
#define S_    2048
#define B_    2
#define H_    16
#define MROWS 4096   // B*S

typedef __attribute__((ext_vector_type(8))) short bf16x8;
typedef __attribute__((ext_vector_type(4))) short short4v;
typedef __attribute__((ext_vector_type(4))) float f32x4;

__device__ __forceinline__ short f2bf(float f) {
  union { float f; unsigned u; } v; v.f = f;
  unsigned r = v.u + 0x7fffu + ((v.u >> 16) & 1u);  // RNE
  return (short)(r >> 16);
}
__device__ __forceinline__ float bf2f(short s) {
  union { unsigned u; float f; } v; v.u = ((unsigned)(unsigned short)s) << 16;
  return v.f;
}
__device__ __forceinline__ void gload_lds16(const void* g, void* l) {
  __builtin_amdgcn_global_load_lds(
      (const __attribute__((address_space(1))) unsigned int*)g,
      (__attribute__((address_space(3))) unsigned int*)l, 16, 0, 0);
}
__device__ __forceinline__ float exp2_fast(float x) {  // exact v_exp_f32 (2^x)
  float r; asm("v_exp_f32 %0, %1" : "=v"(r) : "v"(x)); return r;
}
__device__ __forceinline__ float gelu_f(float v) {
  return 0.5f * v * (1.0f + erff(v * 0.70710678118654752f));
}

// ---------------- fp32 -> bf16 weight convert (4 tensors fused) -----------
__global__ __launch_bounds__(256) void k_cvt4(const float* __restrict__ i0, short* __restrict__ o0, int n0,
                                              const float* __restrict__ i1, short* __restrict__ o1, int n1,
                                              const float* __restrict__ i2, short* __restrict__ o2, int n2,
                                              const float* __restrict__ i3, short* __restrict__ o3, int n3) {
  const float* in; short* out; int n;
  switch (blockIdx.y) {
    case 0: in = i0; out = o0; n = n0; break;
    case 1: in = i1; out = o1; n = n1; break;
    case 2: in = i2; out = o2; n = n2; break;
    default: in = i3; out = o3; n = n3; break;
  }
  int i = blockIdx.x * 256 + threadIdx.x;
  if (i >= n) return;
  float4 v = ((const float4*)in)[i];
  short4v o = { f2bf(v.x), f2bf(v.y), f2bf(v.z), f2bf(v.w) };
  ((short4v*)out)[i] = o;
}

// ---------------- LayerNorm fp32 -> bf16 ----------------
__global__ __launch_bounds__(256) void k_ln(const float* __restrict__ x,
                                            const float* __restrict__ w,
                                            const float* __restrict__ b,
                                            short* __restrict__ out) {
  int row = blockIdx.x;
  int tid = threadIdx.x;
  float4 v = ((const float4*)(x + (size_t)row * E_))[tid];
  float s  = v.x + v.y + v.z + v.w;
  float s2 = v.x*v.x + v.y*v.y + v.z*v.z + v.w*v.w;
  #pragma unroll
  for (int d = 1; d < 64; d <<= 1) { s += __shfl_xor(s, d); s2 += __shfl_xor(s2, d); }
  __shared__ float rs[4], rq[4];
  int wv = tid >> 6;
  if ((tid & 63) == 0) { rs[wv] = s; rq[wv] = s2; }
  __syncthreads();
  s  = rs[0] + rs[1] + rs[2] + rs[3];
  s2 = rq[0] + rq[1] + rq[2] + rq[3];
  float mu  = s * (1.0f / E_);
  float var = fmaxf(s2 * (1.0f / E_) - mu * mu, 0.0f);
  float inv = rsqrtf(var + 1e-6f);
  float4 wv4 = ((const float4*)w)[tid];
  float4 bv4 = ((const float4*)b)[tid];
  short4v o = { f2bf((v.x - mu) * inv * wv4.x + bv4.x),
                f2bf((v.y - mu) * inv * wv4.y + bv4.y),
                f2bf((v.z - mu) * inv * wv4.z + bv4.z),
                f2bf((v.w - mu) * inv * wv4.w + bv4.w) };
  ((short4v*)(out + (size_t)row * E_))[tid] = o;
}

// ---------------- bf16 GEMM: out[m,n] = sum_k A[m,k]*W[n,k] (+epilogue) ----
// EPI: 0 = +bias -> bf16 ; 1 = +bias+res -> fp32 ; 2 = +bias, gelu -> bf16
template <int EPI>
__global__ __launch_bounds__(256) void k_gemm(const short* __restrict__ A,
                                              const short* __restrict__ W,
                                              const float* __restrict__ bias,
                                              const float* __restrict__ res,
                                              void* __restrict__ outv,
                                              int M, int N, int K) {
  __shared__ short As[128 * 32];
  __shared__ short Ws[128 * 32];
  int tid  = threadIdx.x;
  int lane = tid & 63, wave = tid >> 6;
  int wm = wave >> 1, wn = wave & 1;
  int m0 = blockIdx.y * 128, n0 = blockIdx.x * 128;
  int fr = lane & 15, fq = lane >> 4, fk = fq * 8;

  f32x4 acc[4][4];
  #pragma unroll
  for (int i = 0; i < 4; ++i)
    #pragma unroll
    for (int j = 0; j < 4; ++j) acc[i][j] = (f32x4){0.f, 0.f, 0.f, 0.f};

  int sr = tid >> 2;           // staging: flat = tid*8 -> row=tid/4, col=(tid%4)*8
  int sc = (tid & 3) * 8;
  const short* Arow  = A + (size_t)(m0 + sr) * K + sc;
  const short* Wrow  = W + (size_t)(n0 + sr) * K + sc;
  const short* Arow2 = A + (size_t)(m0 + 64 + sr) * K + sc;
  const short* Wrow2 = W + (size_t)(n0 + 64 + sr) * K + sc;
  short* Asl = As + tid * 8;
  short* Wsl = Ws + tid * 8;

  for (int k0 = 0; k0 < K; k0 += 32) {
    __syncthreads();
    gload_lds16(Arow  + k0, Asl);
    gload_lds16(Wrow  + k0, Wsl);
    gload_lds16(Arow2 + k0, Asl + 2048);
    gload_lds16(Wrow2 + k0, Wsl + 2048);
    __syncthreads();
    bf16x8 af[4], bfr[4];
    #pragma unroll
    for (int i = 0; i < 4; ++i) {
      af[i]  = *(const bf16x8*)(As + (wm * 64 + i * 16 + fr) * 32 + fk);
      bfr[i] = *(const bf16x8*)(Ws + (wn * 64 + i * 16 + fr) * 32 + fk);
    }
    #pragma unroll
    for (int mi = 0; mi < 4; ++mi)
      #pragma unroll
      for (int ni = 0; ni < 4; ++ni)
        acc[mi][ni] = __builtin_amdgcn_mfma_f32_16x16x32_bf16(af[mi], bfr[ni],
                                                              acc[mi][ni], 0, 0, 0);
  }

  #pragma unroll
  for (int mi = 0; mi < 4; ++mi) {
    #pragma unroll
    for (int ni = 0; ni < 4; ++ni) {
      int gm0 = m0 + wm * 64 + mi * 16 + fq * 4;
      int gn  = n0 + wn * 64 + ni * 16 + fr;
      float bv = bias[gn];
      #pragma unroll
      for (int j = 0; j < 4; ++j) {
        size_t idx = (size_t)(gm0 + j) * N + gn;
        float v = acc[mi][ni][j] + bv;
        if (EPI == 0)      ((short*)outv)[idx] = f2bf(v);
        else if (EPI == 1) ((float*)outv)[idx] = v + res[idx];
        else               ((short*)outv)[idx] = f2bf(gelu_f(v));
      }
    }
  }
}

// ---------------- causal flash attention (swapped-operand, KVBLK=64) -------
// qkv: [B*S][3072] bf16. out: [B*S][1024] bf16.
// 4 waves; wave w owns 16 q-rows (Q-tile 64). Swapped QK^T: lane owns one
// q-row's scores in-register -> lane-local softmax (only 4 shfl per tile).
// Swapped PV: O^T accum -> lane-local rescale & 1/l. All LDS chunk-XOR
// swizzled with matched write/read sides.
__global__ __launch_bounds__(256) void k_attn(const short* __restrict__ qkv,
                                              short* __restrict__ out) {
  __shared__ short Kt[64 * 64];     // [key][d], chunk-swizzled via global src
  __shared__ short Vt[64 * 64];     // V^T [d][key], chunk-swizzled
  __shared__ short Pl[4][1024];     // per-wave P[q][key] (reused for O)
  int tid  = threadIdx.x;
  int lane = tid & 63, w = tid >> 6;
  int qb   = (int)gridDim.x - 1 - (int)blockIdx.x;   // heavy blocks first
  int q0   = qb * 64;
  int bh   = blockIdx.y;
  int b    = bh >> 4, h = bh & 15;
  int fr   = lane & 15, fq = lane >> 4, fk = fq * 8;
  const float sc = 0.18033688011112042f;   // 0.125 * log2(e) (exp2 domain)

  // Q fragments (B-frag: col=q=fr, k = 32*dd + fq*8 + j), raw bf16
  const short* qp = qkv + (size_t)(b * S_ + q0 + w * 16 + fr) * TE_ + h * 64;
  bf16x8 qa0 = *(const bf16x8*)(qp + fk);
  bf16x8 qa1 = *(const bf16x8*)(qp + 32 + fk);

  float m_r = -__builtin_inff();
  float l_r = 0.f;
  f32x4 o[4];
  #pragma unroll
  for (int c = 0; c < 4; ++c) o[c] = (f32x4){0.f, 0.f, 0.f, 0.f};

  int srow = tid >> 3;      // staging row 0..31 (+32 on round 1)
  int schunk = tid & 7;     // 16B chunk within 128B row
  short* Pw = &Pl[w][0];

  for (int kv = 0; kv <= q0; kv += 64) {
    __syncthreads();
    #pragma unroll
    for (int r = 0; r < 2; ++r) {
      int row = srow + 32 * r;
      size_t grow = (size_t)(b * S_ + kv + row) * TE_ + h * 64;
      // K: pre-swizzled global source -> linear LDS (chunk ^= row&7)
      gload_lds16(qkv + grow + E_ + ((schunk ^ (srow & 7)) << 3),
                  Kt + r * 2048 + tid * 8);
      // V: reg-staged transpose into swizzled V^T
      bf16x8 vv = *(const bf16x8*)(qkv + grow + 2 * E_ + (schunk << 3));
      int kc = row >> 3, kwi = row & 7;
      #pragma unroll
      for (int j = 0; j < 8; ++j) {
        int d = (schunk << 3) + j;
        int csw = kc ^ (d & 7) ^ ((d >> 3) & 7);
        Vt[d * 64 + csw * 8 + kwi] = vv[j];
      }
    }
    __syncthreads();

    // ---- S^T = K @ Q^T : C[key][q], lane owns q=fr, keys 16g+4fq+jj ----
    f32x4 s[4];
    #pragma unroll
    for (int g = 0; g < 4; ++g) {
      const short* kb = Kt + ((g << 4) + fr) * 64;
      int sw = fr & 7;
      bf16x8 a0 = *(const bf16x8*)(kb + ((fq ^ sw) << 3));
      bf16x8 a1 = *(const bf16x8*)(kb + (((4 + fq) ^ sw) << 3));
      f32x4 t = (f32x4){0.f, 0.f, 0.f, 0.f};
      t = __builtin_amdgcn_mfma_f32_16x16x32_bf16(a0, qa0, t, 0, 0, 0);
      t = __builtin_amdgcn_mfma_f32_16x16x32_bf16(a1, qa1, t, 0, 0, 0);
      s[g] = t;
    }
    #pragma unroll
    for (int g = 0; g < 4; ++g)
      #pragma unroll
      for (int jj = 0; jj < 4; ++jj) s[g][jj] *= sc;

    if (kv + 64 > q0) {            // diagonal tile only (block-uniform)
      int qr = (q0 - kv) + 16 * w + fr;
      #pragma unroll
      for (int g = 0; g < 4; ++g)
        #pragma unroll
        for (int jj = 0; jj < 4; ++jj)
          if (16 * g + 4 * fq + jj > qr) s[g][jj] = -__builtin_inff();
    }

    // ---- online softmax: in-lane tree + 2 shfl (over the 4 fq lanes) ----
    float mg0 = fmaxf(fmaxf(s[0][0], s[0][1]), fmaxf(s[0][2], s[0][3]));
    float mg1 = fmaxf(fmaxf(s[1][0], s[1][1]), fmaxf(s[1][2], s[1][3]));
    float mg2 = fmaxf(fmaxf(s[2][0], s[2][1]), fmaxf(s[2][2], s[2][3]));
    float mg3 = fmaxf(fmaxf(s[3][0], s[3][1]), fmaxf(s[3][2], s[3][3]));
    float mt = fmaxf(fmaxf(mg0, mg1), fmaxf(mg2, mg3));
    mt = fmaxf(mt, __shfl_xor(mt, 16));
    mt = fmaxf(mt, __shfl_xor(mt, 32));
    float mn = fmaxf(m_r, mt);
    float al = exp2_fast(m_r - mn);
    m_r = mn;
    #pragma unroll
    for (int g = 0; g < 4; ++g)
      #pragma unroll
      for (int jj = 0; jj < 4; ++jj) s[g][jj] = exp2_fast(s[g][jj] - mn);
    f32x4 s4 = s[0] + s[1] + s[2] + s[3];
    float ps = (s4[0] + s4[1]) + (s4[2] + s4[3]);
    ps += __shfl_xor(ps, 16);
    ps += __shfl_xor(ps, 32);
    l_r = l_r * al + ps;

    // ---- P -> per-wave LDS (bf16, swizzled b64 stores) ----
    #pragma unroll
    for (int g = 0; g < 4; ++g) {
      short4v pk = { f2bf(s[g][0]), f2bf(s[g][1]), f2bf(s[g][2]), f2bf(s[g][3]) };
      int pc = (2 * g + (fq >> 1)) ^ (fr & 7);
      *(short4v*)(Pw + fr * 64 + pc * 8 + ((fq & 1) << 2)) = pk;
    }

    // ---- rescale O (lane-local) ----
    #pragma unroll
    for (int c = 0; c < 4; ++c)
      #pragma unroll
      for (int jj = 0; jj < 4; ++jj) o[c][jj] *= al;

    // ---- O^T += V^T @ P^T : C[d][q] ----
    bf16x8 pb0 = *(const bf16x8*)(Pw + fr * 64 + ((fq ^ (fr & 7)) << 3));
    bf16x8 pb1 = *(const bf16x8*)(Pw + fr * 64 + (((4 + fq) ^ (fr & 7)) << 3));
    #pragma unroll
    for (int c = 0; c < 4; ++c) {
      int d = 16 * c + fr;
      int sbase = (d & 7) ^ ((d >> 3) & 7);
      const short* vb = Vt + d * 64;
      bf16x8 va0 = *(const bf16x8*)(vb + ((fq ^ sbase) << 3));
      bf16x8 va1 = *(const bf16x8*)(vb + (((4 + fq) ^ sbase) << 3));
      o[c] = __builtin_amdgcn_mfma_f32_16x16x32_bf16(va0, pb0, o[c], 0, 0, 0);
      o[c] = __builtin_amdgcn_mfma_f32_16x16x32_bf16(va1, pb1, o[c], 0, 0, 0);
    }
  }

  // ---- epilogue: O^T -> LDS (per-wave, swizzled) -> coalesced global ----
  float inv_l = 1.0f / l_r;
  #pragma unroll
  for (int c = 0; c < 4; ++c) {
    short4v okk = { f2bf(o[c][0] * inv_l), f2bf(o[c][1] * inv_l),
                    f2bf(o[c][2] * inv_l), f2bf(o[c][3] * inv_l) };
    int pc = (2 * c + (fq >> 1)) ^ (fr & 7);
    *(short4v*)(Pw + fr * 64 + pc * 8 + ((fq & 1) << 2)) = okk;
  }
  int ql = lane >> 2, dc = lane & 3;
  int swz = ql & 7;
  const short* ob = Pw + ql * 64;
  bf16x8 r0 = *(const bf16x8*)(ob + (((2 * dc) ^ swz) << 3));
  bf16x8 r1 = *(const bf16x8*)(ob + (((2 * dc + 1) ^ swz) << 3));
  short* op = out + (size_t)(b * S_ + q0 + 16 * w + ql) * E_ + h * 64 + dc * 16;
  *(bf16x8*)op = r0;
  *(bf16x8*)(op + 8) = r1;
}

// ---------------- launch ----------------
extern "C" void kernel_launch(void* const* d_in, const int* in_sizes, int n_in,
                              void* d_out, int out_size, void* d_ws, size_t ws_size,
                              hipStream_t stream) {
  const float* x      = (const float*)d_in[0];
  const float* ln1_w  = (const float*)d_in[1];
  const float* ln1_b  = (const float*)d_in[2];
  const float* qkv_w  = (const float*)d_in[3];
  const float* qkv_b  = (const float*)d_in[4];
  const float* proj_w = (const float*)d_in[5];
  const float* proj_b = (const float*)d_in[6];
  const float* ln2_w  = (const float*)d_in[7];
  const float* ln2_b  = (const float*)d_in[8];
  const float* fc1_w  = (const float*)d_in[9];
  const float* fc1_b  = (const float*)d_in[10];
  const float* fc2_w  = (const float*)d_in[11];
  const float* fc2_b  = (const float*)d_in[12];
  float* out = (float*)d_out;

  char* ws = (char*)d_ws;
  // Timeline-overlapped layout (80 MB total):
  short* xn1    = (short*)(ws + 0);              // 8 MB  (dead after qkv gemm)
  short* qkvb   = (short*)(ws + (8u  << 20));    // 24 MB (dead after attn)
  short* gelu_o = (short*)(ws + 0);              // 32 MB (reuses xn1+qkvb)
  short* attn_o = (short*)(ws + (32u << 20));    // 8 MB  (dead after proj gemm)
  short* h_ln2  = (short*)(ws + (32u << 20));    // 8 MB  (reuses attn_o)
  float* x_res  = (float*)(ws + (40u << 20));    // 16 MB fp32
  short* w_qkv  = (short*)(ws + (56u << 20));    // 6 MB
  short* w_proj = (short*)(ws + (62u << 20));    // 2 MB
  short* w_fc1  = (short*)(ws + (64u << 20));    // 8 MB
  short* w_fc2  = (short*)(ws + (72u << 20));    // 8 MB

  k_cvt4<<<dim3(4096, 4), 256, 0, stream>>>(qkv_w, w_qkv, 786432,
                                            proj_w, w_proj, 262144,
                                            fc1_w, w_fc1, 1048576,
                                            fc2_w, w_fc2, 1048576);

  k_ln<<<MROWS, 256, 0, stream>>>(x, ln1_w, ln1_b, xn1);
  k_gemm<0><<<dim3(24, 32), 256, 0, stream>>>(xn1, w_qkv, qkv_b, nullptr, qkvb,
                                              MROWS, TE_, E_);
  k_attn<<<dim3(S_ / 64, B_ * H_), 256, 0, stream>>>(qkvb, attn_o);
  k_gemm<1><<<dim3(8, 32), 256, 0, stream>>>(attn_o, w_proj, proj_b, x, x_res,
                                             MROWS, E_, E_);
  k_ln<<<MROWS, 256, 0, stream>>>(x_res, ln2_w, ln2_b, h_ln2);
  k_gemm<2><<<dim3(32, 32), 256, 0, stream>>>(h_ln2, w_fc1, fc1_b, nullptr, gelu_o,
                                              MROWS, 4096, E_);
  k_gemm<1><<<dim3(8, 32), 256, 0, stream>>>(gelu_o, w_fc2, fc2_b, x_res, out,
                                             MROWS, E_, 4096);
}

// Round 5
// 413.912 us; speedup vs baseline: 1.3689x; 1.0728x over previous
//
#include <hip/hip_runtime.h>
#include <hip/hip_bf16.h>

// Transformer block fwd: x:[2,2048,1024] fp32. bf16 MFMA GEMMs + flash attn.
// E=1024 H=16 D=64 HID=4096, causal, exact GELU, LN eps=1e-6.

#define E_    1024
#define TE_   3072
#define S_    2048
#define B_    2
#define H_    16
#define MROWS 4096   // B*S

typedef __attribute__((ext_vector_type(8))) short bf16x8;
typedef __attribute__((ext_vector_type(4))) short short4v;
typedef __attribute__((ext_vector_type(4))) float f32x4;

__device__ __forceinline__ short f2bf(float f) {
  union { float f; unsigned u; } v; v.f = f;
  unsigned r = v.u + 0x7fffu + ((v.u >> 16) & 1u);  // RNE
  return (short)(r >> 16);
}
__device__ __forceinline__ float bf2f(short s) {
  union { unsigned u; float f; } v; v.u = ((unsigned)(unsigned short)s) << 16;
  return v.f;
}
__device__ __forceinline__ void gload_lds16(const void* g, void* l) {
  __builtin_amdgcn_global_load_lds(
      (const __attribute__((address_space(1))) unsigned int*)g,
      (__attribute__((address_space(3))) unsigned int*)l, 16, 0, 0);
}
__device__ __forceinline__ float exp2_fast(float x) {  // exact v_exp_f32 (2^x)
  float r; asm("v_exp_f32 %0, %1" : "=v"(r) : "v"(x)); return r;
}
__device__ __forceinline__ float gelu_f(float v) {
  return 0.5f * v * (1.0f + erff(v * 0.70710678118654752f));
}

// ---------------- fp32 -> bf16 weight convert (4 tensors fused) -----------
__global__ __launch_bounds__(256) void k_cvt4(const float* __restrict__ i0, short* __restrict__ o0, int n0,
                                              const float* __restrict__ i1, short* __restrict__ o1, int n1,
                                              const float* __restrict__ i2, short* __restrict__ o2, int n2,
                                              const float* __restrict__ i3, short* __restrict__ o3, int n3) {
  const float* in; short* out; int n;
  switch (blockIdx.y) {
    case 0: in = i0; out = o0; n = n0; break;
    case 1: in = i1; out = o1; n = n1; break;
    case 2: in = i2; out = o2; n = n2; break;
    default: in = i3; out = o3; n = n3; break;
  }
  int i = blockIdx.x * 256 + threadIdx.x;
  if (i >= n) return;
  float4 v = ((const float4*)in)[i];
  short4v o = { f2bf(v.x), f2bf(v.y), f2bf(v.z), f2bf(v.w) };
  ((short4v*)out)[i] = o;
}

// ---------------- LayerNorm fp32 -> bf16 ----------------
__global__ __launch_bounds__(256) void k_ln(const float* __restrict__ x,
                                            const float* __restrict__ w,
                                            const float* __restrict__ b,
                                            short* __restrict__ out) {
  int row = blockIdx.x;
  int tid = threadIdx.x;
  float4 v = ((const float4*)(x + (size_t)row * E_))[tid];
  float s  = v.x + v.y + v.z + v.w;
  float s2 = v.x*v.x + v.y*v.y + v.z*v.z + v.w*v.w;
  #pragma unroll
  for (int d = 1; d < 64; d <<= 1) { s += __shfl_xor(s, d); s2 += __shfl_xor(s2, d); }
  __shared__ float rs[4], rq[4];
  int wv = tid >> 6;
  if ((tid & 63) == 0) { rs[wv] = s; rq[wv] = s2; }
  __syncthreads();
  s  = rs[0] + rs[1] + rs[2] + rs[3];
  s2 = rq[0] + rq[1] + rq[2] + rq[3];
  float mu  = s * (1.0f / E_);
  float var = fmaxf(s2 * (1.0f / E_) - mu * mu, 0.0f);
  float inv = rsqrtf(var + 1e-6f);
  float4 wv4 = ((const float4*)w)[tid];
  float4 bv4 = ((const float4*)b)[tid];
  short4v o = { f2bf((v.x - mu) * inv * wv4.x + bv4.x),
                f2bf((v.y - mu) * inv * wv4.y + bv4.y),
                f2bf((v.z - mu) * inv * wv4.z + bv4.z),
                f2bf((v.w - mu) * inv * wv4.w + bv4.w) };
  ((short4v*)(out + (size_t)row * E_))[tid] = o;
}

// ---------------- bf16 GEMM: out[m,n] = sum_k A[m,k]*W[n,k] (+epilogue) ----
// 2-phase double-buffered pipeline (T3-minimum): STAGE(t+1) issued BEFORE
// compute(t); single vmcnt-drain barrier per K-step, loads fly over MFMA.
// EPI: 0 = +bias -> bf16 ; 1 = +bias+res -> fp32 ; 2 = +bias, gelu -> bf16
template <int EPI>
__global__ __launch_bounds__(256, 3) void k_gemm(const short* __restrict__ A,
                                                 const short* __restrict__ W,
                                                 const float* __restrict__ bias,
                                                 const float* __restrict__ res,
                                                 void* __restrict__ outv,
                                                 int M, int N, int K) {
  __shared__ short As[2][128 * 32];
  __shared__ short Ws[2][128 * 32];
  int tid  = threadIdx.x;
  int lane = tid & 63, wave = tid >> 6;
  int wm = wave >> 1, wn = wave & 1;
  int m0 = blockIdx.y * 128, n0 = blockIdx.x * 128;
  int fr = lane & 15, fq = lane >> 4, fk = fq * 8;

  f32x4 acc[4][4];
  #pragma unroll
  for (int i = 0; i < 4; ++i)
    #pragma unroll
    for (int j = 0; j < 4; ++j) acc[i][j] = (f32x4){0.f, 0.f, 0.f, 0.f};

  int sr = tid >> 2;           // staging: row = tid/4, col = (tid%4)*8
  int sc = (tid & 3) * 8;
  const short* Arow  = A + (size_t)(m0 + sr) * K + sc;
  const short* Wrow  = W + (size_t)(n0 + sr) * K + sc;
  const short* Arow2 = A + (size_t)(m0 + 64 + sr) * K + sc;
  const short* Wrow2 = W + (size_t)(n0 + 64 + sr) * K + sc;

#define STAGE_(buf, k0)                                   \
  do {                                                    \
    gload_lds16(Arow  + (k0), &As[buf][tid * 8]);         \
    gload_lds16(Arow2 + (k0), &As[buf][2048 + tid * 8]);  \
    gload_lds16(Wrow  + (k0), &Ws[buf][tid * 8]);         \
    gload_lds16(Wrow2 + (k0), &Ws[buf][2048 + tid * 8]);  \
  } while (0)

#define COMPUTE_(buf)                                                         \
  do {                                                                        \
    bf16x8 af[4], bfr[4];                                                     \
    _Pragma("unroll")                                                         \
    for (int i = 0; i < 4; ++i) {                                             \
      af[i]  = *(const bf16x8*)(&As[buf][(wm * 64 + i * 16 + fr) * 32 + fk]); \
      bfr[i] = *(const bf16x8*)(&Ws[buf][(wn * 64 + i * 16 + fr) * 32 + fk]); \
    }                                                                         \
    _Pragma("unroll")                                                         \
    for (int mi = 0; mi < 4; ++mi)                                            \
      _Pragma("unroll")                                                       \
      for (int ni = 0; ni < 4; ++ni)                                          \
        acc[mi][ni] = __builtin_amdgcn_mfma_f32_16x16x32_bf16(                \
            af[mi], bfr[ni], acc[mi][ni], 0, 0, 0);                           \
  } while (0)

  int nt = K >> 5;
  STAGE_(0, 0);
  __syncthreads();                 // drains vmcnt(0): buf0 ready
  int cur = 0;
  for (int t = 0; t < nt - 1; ++t) {
    STAGE_(cur ^ 1, (t + 1) * 32); // in flight across the compute below
    COMPUTE_(cur);
    __syncthreads();               // drain: next buffer ready, reads of cur done
    cur ^= 1;
  }
  COMPUTE_(cur);                   // last tile, no stage

#undef STAGE_
#undef COMPUTE_

  #pragma unroll
  for (int mi = 0; mi < 4; ++mi) {
    #pragma unroll
    for (int ni = 0; ni < 4; ++ni) {
      int gm0 = m0 + wm * 64 + mi * 16 + fq * 4;
      int gn  = n0 + wn * 64 + ni * 16 + fr;
      float bv = bias[gn];
      #pragma unroll
      for (int j = 0; j < 4; ++j) {
        size_t idx = (size_t)(gm0 + j) * N + gn;
        float v = acc[mi][ni][j] + bv;
        if (EPI == 0)      ((short*)outv)[idx] = f2bf(v);
        else if (EPI == 1) ((float*)outv)[idx] = v + res[idx];
        else               ((short*)outv)[idx] = f2bf(gelu_f(v));
      }
    }
  }
}

// ---------------- causal flash attention (swapped-operand, KVBLK=64) -------
// qkv: [B*S][3072] bf16. out: [B*S][1024] bf16.
// 4 waves; wave w owns 16 q-rows (Q-tile 64). Swapped QK^T: lane owns one
// q-row's scores in-register -> lane-local softmax (only 4 shfl per tile).
// Swapped PV: O^T accum -> lane-local rescale & 1/l. All LDS chunk-XOR
// swizzled with matched write/read sides.
__global__ __launch_bounds__(256) void k_attn(const short* __restrict__ qkv,
                                              short* __restrict__ out) {
  __shared__ short Kt[64 * 64];     // [key][d], chunk-swizzled via global src
  __shared__ short Vt[64 * 64];     // V^T [d][key], chunk-swizzled
  __shared__ short Pl[4][1024];     // per-wave P[q][key] (reused for O)
  int tid  = threadIdx.x;
  int lane = tid & 63, w = tid >> 6;
  int qb   = (int)gridDim.x - 1 - (int)blockIdx.x;   // heavy blocks first
  int q0   = qb * 64;
  int bh   = blockIdx.y;
  int b    = bh >> 4, h = bh & 15;
  int fr   = lane & 15, fq = lane >> 4, fk = fq * 8;
  const float sc = 0.18033688011112042f;   // 0.125 * log2(e) (exp2 domain)

  // Q fragments (B-frag: col=q=fr, k = 32*dd + fq*8 + j), raw bf16
  const short* qp = qkv + (size_t)(b * S_ + q0 + w * 16 + fr) * TE_ + h * 64;
  bf16x8 qa0 = *(const bf16x8*)(qp + fk);
  bf16x8 qa1 = *(const bf16x8*)(qp + 32 + fk);

  float m_r = -__builtin_inff();
  float l_r = 0.f;
  f32x4 o[4];
  #pragma unroll
  for (int c = 0; c < 4; ++c) o[c] = (f32x4){0.f, 0.f, 0.f, 0.f};

  int srow = tid >> 3;      // staging row 0..31 (+32 on round 1)
  int schunk = tid & 7;     // 16B chunk within 128B row
  short* Pw = &Pl[w][0];

  for (int kv = 0; kv <= q0; kv += 64) {
    __syncthreads();
    #pragma unroll
    for (int r = 0; r < 2; ++r) {
      int row = srow + 32 * r;
      size_t grow = (size_t)(b * S_ + kv + row) * TE_ + h * 64;
      // K: pre-swizzled global source -> linear LDS (chunk ^= row&7)
      gload_lds16(qkv + grow + E_ + ((schunk ^ (srow & 7)) << 3),
                  Kt + r * 2048 + tid * 8);
      // V: reg-staged transpose into swizzled V^T
      bf16x8 vv = *(const bf16x8*)(qkv + grow + 2 * E_ + (schunk << 3));
      int kc = row >> 3, kwi = row & 7;
      #pragma unroll
      for (int j = 0; j < 8; ++j) {
        int d = (schunk << 3) + j;
        int csw = kc ^ (d & 7) ^ ((d >> 3) & 7);
        Vt[d * 64 + csw * 8 + kwi] = vv[j];
      }
    }
    __syncthreads();

    // ---- S^T = K @ Q^T : C[key][q], lane owns q=fr, keys 16g+4fq+jj ----
    f32x4 s[4];
    #pragma unroll
    for (int g = 0; g < 4; ++g) {
      const short* kb = Kt + ((g << 4) + fr) * 64;
      int sw = fr & 7;
      bf16x8 a0 = *(const bf16x8*)(kb + ((fq ^ sw) << 3));
      bf16x8 a1 = *(const bf16x8*)(kb + (((4 + fq) ^ sw) << 3));
      f32x4 t = (f32x4){0.f, 0.f, 0.f, 0.f};
      t = __builtin_amdgcn_mfma_f32_16x16x32_bf16(a0, qa0, t, 0, 0, 0);
      t = __builtin_amdgcn_mfma_f32_16x16x32_bf16(a1, qa1, t, 0, 0, 0);
      s[g] = t;
    }
    #pragma unroll
    for (int g = 0; g < 4; ++g)
      #pragma unroll
      for (int jj = 0; jj < 4; ++jj) s[g][jj] *= sc;

    if (kv + 64 > q0) {            // diagonal tile only (block-uniform)
      int qr = (q0 - kv) + 16 * w + fr;
      #pragma unroll
      for (int g = 0; g < 4; ++g)
        #pragma unroll
        for (int jj = 0; jj < 4; ++jj)
          if (16 * g + 4 * fq + jj > qr) s[g][jj] = -__builtin_inff();
    }

    // ---- online softmax: in-lane tree + 2 shfl (over the 4 fq lanes) ----
    float mg0 = fmaxf(fmaxf(s[0][0], s[0][1]), fmaxf(s[0][2], s[0][3]));
    float mg1 = fmaxf(fmaxf(s[1][0], s[1][1]), fmaxf(s[1][2], s[1][3]));
    float mg2 = fmaxf(fmaxf(s[2][0], s[2][1]), fmaxf(s[2][2], s[2][3]));
    float mg3 = fmaxf(fmaxf(s[3][0], s[3][1]), fmaxf(s[3][2], s[3][3]));
    float mt = fmaxf(fmaxf(mg0, mg1), fmaxf(mg2, mg3));
    mt = fmaxf(mt, __shfl_xor(mt, 16));
    mt = fmaxf(mt, __shfl_xor(mt, 32));
    float mn = fmaxf(m_r, mt);
    float al = exp2_fast(m_r - mn);
    m_r = mn;
    #pragma unroll
    for (int g = 0; g < 4; ++g)
      #pragma unroll
      for (int jj = 0; jj < 4; ++jj) s[g][jj] = exp2_fast(s[g][jj] - mn);
    f32x4 s4 = s[0] + s[1] + s[2] + s[3];
    float ps = (s4[0] + s4[1]) + (s4[2] + s4[3]);
    ps += __shfl_xor(ps, 16);
    ps += __shfl_xor(ps, 32);
    l_r = l_r * al + ps;

    // ---- P -> per-wave LDS (bf16, swizzled b64 stores) ----
    #pragma unroll
    for (int g = 0; g < 4; ++g) {
      short4v pk = { f2bf(s[g][0]), f2bf(s[g][1]), f2bf(s[g][2]), f2bf(s[g][3]) };
      int pc = (2 * g + (fq >> 1)) ^ (fr & 7);
      *(short4v*)(Pw + fr * 64 + pc * 8 + ((fq & 1) << 2)) = pk;
    }

    // ---- rescale O (lane-local) ----
    #pragma unroll
    for (int c = 0; c < 4; ++c)
      #pragma unroll
      for (int jj = 0; jj < 4; ++jj) o[c][jj] *= al;

    // ---- O^T += V^T @ P^T : C[d][q] ----
    bf16x8 pb0 = *(const bf16x8*)(Pw + fr * 64 + ((fq ^ (fr & 7)) << 3));
    bf16x8 pb1 = *(const bf16x8*)(Pw + fr * 64 + (((4 + fq) ^ (fr & 7)) << 3));
    #pragma unroll
    for (int c = 0; c < 4; ++c) {
      int d = 16 * c + fr;
      int sbase = (d & 7) ^ ((d >> 3) & 7);
      const short* vb = Vt + d * 64;
      bf16x8 va0 = *(const bf16x8*)(vb + ((fq ^ sbase) << 3));
      bf16x8 va1 = *(const bf16x8*)(vb + (((4 + fq) ^ sbase) << 3));
      o[c] = __builtin_amdgcn_mfma_f32_16x16x32_bf16(va0, pb0, o[c], 0, 0, 0);
      o[c] = __builtin_amdgcn_mfma_f32_16x16x32_bf16(va1, pb1, o[c], 0, 0, 0);
    }
  }

  // ---- epilogue: O^T -> LDS (per-wave, swizzled) -> coalesced global ----
  float inv_l = 1.0f / l_r;
  #pragma unroll
  for (int c = 0; c < 4; ++c) {
    short4v okk = { f2bf(o[c][0] * inv_l), f2bf(o[c][1] * inv_l),
                    f2bf(o[c][2] * inv_l), f2bf(o[c][3] * inv_l) };
    int pc = (2 * c + (fq >> 1)) ^ (fr & 7);
    *(short4v*)(Pw + fr * 64 + pc * 8 + ((fq & 1) << 2)) = okk;
  }
  int ql = lane >> 2, dc = lane & 3;
  int swz = ql & 7;
  const short* ob = Pw + ql * 64;
  bf16x8 r0 = *(const bf16x8*)(ob + (((2 * dc) ^ swz) << 3));
  bf16x8 r1 = *(const bf16x8*)(ob + (((2 * dc + 1) ^ swz) << 3));
  short* op = out + (size_t)(b * S_ + q0 + 16 * w + ql) * E_ + h * 64 + dc * 16;
  *(bf16x8*)op = r0;
  *(bf16x8*)(op + 8) = r1;
}

// ---------------- launch ----------------
extern "C" void kernel_launch(void* const* d_in, const int* in_sizes, int n_in,
                              void* d_out, int out_size, void* d_ws, size_t ws_size,
                              hipStream_t stream) {
  const float* x      = (const float*)d_in[0];
  const float* ln1_w  = (const float*)d_in[1];
  const float* ln1_b  = (const float*)d_in[2];
  const float* qkv_w  = (const float*)d_in[3];
  const float* qkv_b  = (const float*)d_in[4];
  const float* proj_w = (const float*)d_in[5];
  const float* proj_b = (const float*)d_in[6];
  const float* ln2_w  = (const float*)d_in[7];
  const float* ln2_b  = (const float*)d_in[8];
  const float* fc1_w  = (const float*)d_in[9];
  const float* fc1_b  = (const float*)d_in[10];
  const float* fc2_w  = (const float*)d_in[11];
  const float* fc2_b  = (const float*)d_in[12];
  float* out = (float*)d_out;

  char* ws = (char*)d_ws;
  // Timeline-overlapped layout (80 MB total):
  short* xn1    = (short*)(ws + 0);              // 8 MB  (dead after qkv gemm)
  short* qkvb   = (short*)(ws + (8u  << 20));    // 24 MB (dead after attn)
  short* gelu_o = (short*)(ws + 0);              // 32 MB (reuses xn1+qkvb)
  short* attn_o = (short*)(ws + (32u << 20));    // 8 MB  (dead after proj gemm)
  short* h_ln2  = (short*)(ws + (32u << 20));    // 8 MB  (reuses attn_o)
  float* x_res  = (float*)(ws + (40u << 20));    // 16 MB fp32
  short* w_qkv  = (short*)(ws + (56u << 20));    // 6 MB
  short* w_proj = (short*)(ws + (62u << 20));    // 2 MB
  short* w_fc1  = (short*)(ws + (64u << 20));    // 8 MB
  short* w_fc2  = (short*)(ws + (72u << 20));    // 8 MB

  k_cvt4<<<dim3(4096, 4), 256, 0, stream>>>(qkv_w, w_qkv, 786432,
                                            proj_w, w_proj, 262144,
                                            fc1_w, w_fc1, 1048576,
                                            fc2_w, w_fc2, 1048576);

  k_ln<<<MROWS, 256, 0, stream>>>(x, ln1_w, ln1_b, xn1);
  k_gemm<0><<<dim3(24, 32), 256, 0, stream>>>(xn1, w_qkv, qkv_b, nullptr, qkvb,
                                              MROWS, TE_, E_);
  k_attn<<<dim3(S_ / 64, B_ * H_), 256, 0, stream>>>(qkvb, attn_o);
  k_gemm<1><<<dim3(8, 32), 256, 0, stream>>>(attn_o, w_proj, proj_b, x, x_res,
                                             MROWS, E_, E_);
  k_ln<<<MROWS, 256, 0, stream>>>(x_res, ln2_w, ln2_b, h_ln2);
  k_gemm<2><<<dim3(32, 32), 256, 0, stream>>>(h_ln2, w_fc1, fc1_b, nullptr, gelu_o,
                                              MROWS, 4096, E_);
  k_gemm<1><<<dim3(8, 32), 256, 0, stream>>>(gelu_o, w_fc2, fc2_b, x_res, out,
                                             MROWS, E_, 4096);
}

// Round 7
// 396.369 us; speedup vs baseline: 1.4295x; 1.0443x over previous
//
#include <hip/hip_runtime.h>
#include <hip/hip_bf16.h>

// Transformer block fwd: x:[2,2048,1024] fp32. bf16 MFMA GEMMs + flash attn.
// E=1024 H=16 D=64 HID=4096, causal, exact GELU, LN eps=1e-6.

#define E_    1024
#define TE_   3072
#define S_    2048
#define B_    2
#define H_    16
#define MROWS 4096   // B*S

typedef __attribute__((ext_vector_type(8))) short bf16x8;
typedef __attribute__((ext_vector_type(4))) short short4v;
typedef __attribute__((ext_vector_type(4))) float f32x4;

__device__ __forceinline__ short f2bf(float f) {
  union { float f; unsigned u; } v; v.f = f;
  unsigned r = v.u + 0x7fffu + ((v.u >> 16) & 1u);  // RNE
  return (short)(r >> 16);
}
__device__ __forceinline__ float bf2f(short s) {
  union { unsigned u; float f; } v; v.u = ((unsigned)(unsigned short)s) << 16;
  return v.f;
}
__device__ __forceinline__ void gload_lds16(const void* g, void* l) {
  __builtin_amdgcn_global_load_lds(
      (const __attribute__((address_space(1))) unsigned int*)g,
      (__attribute__((address_space(3))) unsigned int*)l, 16, 0, 0);
}
__device__ __forceinline__ float exp2_fast(float x) {  // exact v_exp_f32 (2^x)
  float r; asm("v_exp_f32 %0, %1" : "=v"(r) : "v"(x)); return r;
}
__device__ __forceinline__ float gelu_f(float v) {
  return 0.5f * v * (1.0f + erff(v * 0.70710678118654752f));
}

// ---------------- fp32 -> bf16 weight convert (4 tensors fused) -----------
__global__ __launch_bounds__(256) void k_cvt4(const float* __restrict__ i0, short* __restrict__ o0, int n0,
                                              const float* __restrict__ i1, short* __restrict__ o1, int n1,
                                              const float* __restrict__ i2, short* __restrict__ o2, int n2,
                                              const float* __restrict__ i3, short* __restrict__ o3, int n3) {
  const float* in; short* out; int n;
  switch (blockIdx.y) {
    case 0: in = i0; out = o0; n = n0; break;
    case 1: in = i1; out = o1; n = n1; break;
    case 2: in = i2; out = o2; n = n2; break;
    default: in = i3; out = o3; n = n3; break;
  }
  int i = blockIdx.x * 256 + threadIdx.x;
  if (i >= n) return;
  float4 v = ((const float4*)in)[i];
  short4v o = { f2bf(v.x), f2bf(v.y), f2bf(v.z), f2bf(v.w) };
  ((short4v*)out)[i] = o;
}

// ---------------- LayerNorm fp32 -> bf16 ----------------
__global__ __launch_bounds__(256) void k_ln(const float* __restrict__ x,
                                            const float* __restrict__ w,
                                            const float* __restrict__ b,
                                            short* __restrict__ out) {
  int row = blockIdx.x;
  int tid = threadIdx.x;
  float4 v = ((const float4*)(x + (size_t)row * E_))[tid];
  float s  = v.x + v.y + v.z + v.w;
  float s2 = v.x*v.x + v.y*v.y + v.z*v.z + v.w*v.w;
  #pragma unroll
  for (int d = 1; d < 64; d <<= 1) { s += __shfl_xor(s, d); s2 += __shfl_xor(s2, d); }
  __shared__ float rs[4], rq[4];
  int wv = tid >> 6;
  if ((tid & 63) == 0) { rs[wv] = s; rq[wv] = s2; }
  __syncthreads();
  s  = rs[0] + rs[1] + rs[2] + rs[3];
  s2 = rq[0] + rq[1] + rq[2] + rq[3];
  float mu  = s * (1.0f / E_);
  float var = fmaxf(s2 * (1.0f / E_) - mu * mu, 0.0f);
  float inv = rsqrtf(var + 1e-6f);
  float4 wv4 = ((const float4*)w)[tid];
  float4 bv4 = ((const float4*)b)[tid];
  short4v o = { f2bf((v.x - mu) * inv * wv4.x + bv4.x),
                f2bf((v.y - mu) * inv * wv4.y + bv4.y),
                f2bf((v.z - mu) * inv * wv4.z + bv4.z),
                f2bf((v.w - mu) * inv * wv4.w + bv4.w) };
  ((short4v*)(out + (size_t)row * E_))[tid] = o;
}

// ---------------- bf16 GEMM: out[m,n] = sum_k A[m,k]*W[n,k] (+epilogue) ----
// 2-phase double-buffered pipeline: STAGE(t+1) issued BEFORE compute(t);
// single drain barrier per K-step.
// EPI: 0 = +bias -> bf16 ; 1 = +bias+res -> fp32 ; 2 = +bias, gelu -> bf16
template <int EPI>
__global__ __launch_bounds__(256, 3) void k_gemm(const short* __restrict__ A,
                                                 const short* __restrict__ W,
                                                 const float* __restrict__ bias,
                                                 const float* __restrict__ res,
                                                 void* __restrict__ outv,
                                                 int M, int N, int K) {
  __shared__ short As[2][128 * 32];
  __shared__ short Ws[2][128 * 32];
  int tid  = threadIdx.x;
  int lane = tid & 63, wave = tid >> 6;
  int wm = wave >> 1, wn = wave & 1;
  int m0 = blockIdx.y * 128, n0 = blockIdx.x * 128;
  int fr = lane & 15, fq = lane >> 4, fk = fq * 8;

  f32x4 acc[4][4];
  #pragma unroll
  for (int i = 0; i < 4; ++i)
    #pragma unroll
    for (int j = 0; j < 4; ++j) acc[i][j] = (f32x4){0.f, 0.f, 0.f, 0.f};

  int sr = tid >> 2;           // staging: row = tid/4, col = (tid%4)*8
  int sc = (tid & 3) * 8;
  const short* Arow  = A + (size_t)(m0 + sr) * K + sc;
  const short* Wrow  = W + (size_t)(n0 + sr) * K + sc;
  const short* Arow2 = A + (size_t)(m0 + 64 + sr) * K + sc;
  const short* Wrow2 = W + (size_t)(n0 + 64 + sr) * K + sc;

#define STAGE_(buf, k0)                                   \
  do {                                                    \
    gload_lds16(Arow  + (k0), &As[buf][tid * 8]);         \
    gload_lds16(Arow2 + (k0), &As[buf][2048 + tid * 8]);  \
    gload_lds16(Wrow  + (k0), &Ws[buf][tid * 8]);         \
    gload_lds16(Wrow2 + (k0), &Ws[buf][2048 + tid * 8]);  \
  } while (0)

#define COMPUTE_(buf)                                                         \
  do {                                                                        \
    bf16x8 af[4], bfr[4];                                                     \
    _Pragma("unroll")                                                         \
    for (int i = 0; i < 4; ++i) {                                             \
      af[i]  = *(const bf16x8*)(&As[buf][(wm * 64 + i * 16 + fr) * 32 + fk]); \
      bfr[i] = *(const bf16x8*)(&Ws[buf][(wn * 64 + i * 16 + fr) * 32 + fk]); \
    }                                                                         \
    _Pragma("unroll")                                                         \
    for (int mi = 0; mi < 4; ++mi)                                            \
      _Pragma("unroll")                                                       \
      for (int ni = 0; ni < 4; ++ni)                                          \
        acc[mi][ni] = __builtin_amdgcn_mfma_f32_16x16x32_bf16(                \
            af[mi], bfr[ni], acc[mi][ni], 0, 0, 0);                           \
  } while (0)

  int nt = K >> 5;
  STAGE_(0, 0);
  __syncthreads();                 // drains vmcnt(0): buf0 ready
  int cur = 0;
  for (int t = 0; t < nt - 1; ++t) {
    STAGE_(cur ^ 1, (t + 1) * 32); // in flight across the compute below
    COMPUTE_(cur);
    __syncthreads();               // drain: next buffer ready, reads of cur done
    cur ^= 1;
  }
  COMPUTE_(cur);                   // last tile, no stage

#undef STAGE_
#undef COMPUTE_

  #pragma unroll
  for (int mi = 0; mi < 4; ++mi) {
    #pragma unroll
    for (int ni = 0; ni < 4; ++ni) {
      int gm0 = m0 + wm * 64 + mi * 16 + fq * 4;
      int gn  = n0 + wn * 64 + ni * 16 + fr;
      float bv = bias[gn];
      #pragma unroll
      for (int j = 0; j < 4; ++j) {
        size_t idx = (size_t)(gm0 + j) * N + gn;
        float v = acc[mi][ni][j] + bv;
        if (EPI == 0)      ((short*)outv)[idx] = f2bf(v);
        else if (EPI == 1) ((float*)outv)[idx] = v + res[idx];
        else               ((short*)outv)[idx] = f2bf(gelu_f(v));
      }
    }
  }
}

// ---------------- causal flash attention (swapped-operand) ----------------
// QBLK=128 (4 waves x 32 q-rows as 2 fragment-groups), KVBLK=64,
// double-buffered K/V with prefetch: issue loads for tile t+1 before
// compute(t), V-reg->LDS write after compute, ONE barrier per tile.
// Swapped QK^T/PV: lane owns one q-row -> lane-local softmax/rescale.
__global__ __launch_bounds__(256, 3) void k_attn(const short* __restrict__ qkv,
                                                 short* __restrict__ out) {
  __shared__ short Kt[2][64 * 64];   // [key][d] swizzled via global src
  __shared__ short Vt[2][64 * 64];   // V^T [d][key] swizzled
  __shared__ short Pl[4][2048];      // per-wave P (2 q-groups), reused for O
  int tid  = threadIdx.x;
  int lane = tid & 63, w = tid >> 6;
  int qb   = (int)gridDim.x - 1 - (int)blockIdx.x;   // heavy blocks first
  int q0   = qb * 128;
  int bh   = blockIdx.y;
  int b    = bh >> 4, h = bh & 15;
  int fr   = lane & 15, fq = lane >> 4, fk = fq * 8;
  const float sc = 0.18033688011112042f;   // 0.125 * log2(e) (exp2 domain)

  // Q fragments: group g2 covers q-rows q0+w*32+g2*16+fr
  bf16x8 qa[2][2];
  #pragma unroll
  for (int g2 = 0; g2 < 2; ++g2) {
    const short* qp = qkv + (size_t)(b * S_ + q0 + w * 32 + g2 * 16 + fr) * TE_ + h * 64;
    qa[g2][0] = *(const bf16x8*)(qp + fk);
    qa[g2][1] = *(const bf16x8*)(qp + 32 + fk);
  }

  float m_r[2] = {-__builtin_inff(), -__builtin_inff()};
  float l_r[2] = {0.f, 0.f};
  f32x4 o[2][4];
  #pragma unroll
  for (int g2 = 0; g2 < 2; ++g2)
    #pragma unroll
    for (int c = 0; c < 4; ++c) o[g2][c] = (f32x4){0.f, 0.f, 0.f, 0.f};

  int srow = tid >> 3;      // staging row 0..31 (+32 on round 1)
  int schunk = tid & 7;     // 16B chunk within 128B row
  short* Pw = &Pl[w][0];
  bf16x8 vv[2];

#define V_LOAD_(kvv)                                                          \
  do {                                                                        \
    _Pragma("unroll")                                                         \
    for (int r = 0; r < 2; ++r) {                                             \
      size_t grow = (size_t)(b * S_ + (kvv) + srow + 32 * r) * TE_ + h * 64;  \
      vv[r] = *(const bf16x8*)(qkv + grow + 2 * E_ + (schunk << 3));          \
    }                                                                         \
  } while (0)

#define K_STAGE_(buf, kvv)                                                    \
  do {                                                                        \
    _Pragma("unroll")                                                         \
    for (int r = 0; r < 2; ++r) {                                             \
      size_t grow = (size_t)(b * S_ + (kvv) + srow + 32 * r) * TE_ + h * 64;  \
      gload_lds16(qkv + grow + E_ + ((schunk ^ (srow & 7)) << 3),             \
                  &Kt[buf][r * 2048 + tid * 8]);                              \
    }                                                                         \
  } while (0)

#define V_WRITE_(buf)                                                         \
  do {                                                                        \
    _Pragma("unroll")                                                         \
    for (int r = 0; r < 2; ++r) {                                             \
      int row = srow + 32 * r;                                                \
      int kc = row >> 3, kwi = row & 7;                                       \
      _Pragma("unroll")                                                       \
      for (int j = 0; j < 8; ++j) {                                           \
        int d = (schunk << 3) + j;                                            \
        int csw = kc ^ (d & 7) ^ ((d >> 3) & 7);                              \
        Vt[buf][d * 64 + csw * 8 + kwi] = vv[r][j];                           \
      }                                                                       \
    }                                                                         \
  } while (0)

  // prologue: stage tile 0 into buf 0
  V_LOAD_(0);
  K_STAGE_(0, 0);
  V_WRITE_(0);
  __syncthreads();
  int cur = 0;
  int nt = 2 * qb + 2;

  for (int t = 0; t < nt; ++t) {
    int kv = t * 64;
    if (t + 1 < nt) {             // prefetch next tile (in flight over compute)
      V_LOAD_((t + 1) * 64);
      K_STAGE_(cur ^ 1, (t + 1) * 64);
    }

    // ---- K A-frags (shared by both q-groups) ----
    int sw = fr & 7;
    bf16x8 ka[4][2];
    #pragma unroll
    for (int g = 0; g < 4; ++g) {
      const short* kb = &Kt[cur][((g << 4) + fr) * 64];
      ka[g][0] = *(const bf16x8*)(kb + ((fq ^ sw) << 3));
      ka[g][1] = *(const bf16x8*)(kb + (((4 + fq) ^ sw) << 3));
    }
    // ---- S^T = K @ Q^T : lane owns q=fr (per group), keys 16g+4fq+jj ----
    f32x4 s[2][4];
    #pragma unroll
    for (int g2 = 0; g2 < 2; ++g2)
      #pragma unroll
      for (int g = 0; g < 4; ++g) {
        f32x4 t0 = (f32x4){0.f, 0.f, 0.f, 0.f};
        t0 = __builtin_amdgcn_mfma_f32_16x16x32_bf16(ka[g][0], qa[g2][0], t0, 0, 0, 0);
        t0 = __builtin_amdgcn_mfma_f32_16x16x32_bf16(ka[g][1], qa[g2][1], t0, 0, 0, 0);
        s[g2][g] = t0;
      }
    #pragma unroll
    for (int g2 = 0; g2 < 2; ++g2)
      #pragma unroll
      for (int g = 0; g < 4; ++g)
        #pragma unroll
        for (int jj = 0; jj < 4; ++jj) s[g2][g][jj] *= sc;

    if (kv + 64 > q0) {            // diagonal region (block-uniform test)
      #pragma unroll
      for (int g2 = 0; g2 < 2; ++g2) {
        int qr = (q0 - kv) + 32 * w + 16 * g2 + fr;
        #pragma unroll
        for (int g = 0; g < 4; ++g)
          #pragma unroll
          for (int jj = 0; jj < 4; ++jj)
            if (16 * g + 4 * fq + jj > qr) s[g2][g][jj] = -__builtin_inff();
      }
    }

    // ---- online softmax per q-group: in-lane tree + 2 shfl ----
    #pragma unroll
    for (int g2 = 0; g2 < 2; ++g2) {
      float mg0 = fmaxf(fmaxf(s[g2][0][0], s[g2][0][1]), fmaxf(s[g2][0][2], s[g2][0][3]));
      float mg1 = fmaxf(fmaxf(s[g2][1][0], s[g2][1][1]), fmaxf(s[g2][1][2], s[g2][1][3]));
      float mg2 = fmaxf(fmaxf(s[g2][2][0], s[g2][2][1]), fmaxf(s[g2][2][2], s[g2][2][3]));
      float mg3 = fmaxf(fmaxf(s[g2][3][0], s[g2][3][1]), fmaxf(s[g2][3][2], s[g2][3][3]));
      float mt = fmaxf(fmaxf(mg0, mg1), fmaxf(mg2, mg3));
      mt = fmaxf(mt, __shfl_xor(mt, 16));
      mt = fmaxf(mt, __shfl_xor(mt, 32));
      float mn = fmaxf(m_r[g2], mt);
      float al = exp2_fast(m_r[g2] - mn);
      m_r[g2] = mn;
      #pragma unroll
      for (int g = 0; g < 4; ++g)
        #pragma unroll
        for (int jj = 0; jj < 4; ++jj) s[g2][g][jj] = exp2_fast(s[g2][g][jj] - mn);
      f32x4 s4 = s[g2][0] + s[g2][1] + s[g2][2] + s[g2][3];
      float ps = (s4[0] + s4[1]) + (s4[2] + s4[3]);
      ps += __shfl_xor(ps, 16);
      ps += __shfl_xor(ps, 32);
      l_r[g2] = l_r[g2] * al + ps;

      // P -> per-wave LDS (bf16, swizzled b64 stores)
      #pragma unroll
      for (int g = 0; g < 4; ++g) {
        short4v pk = { f2bf(s[g2][g][0]), f2bf(s[g2][g][1]),
                       f2bf(s[g2][g][2]), f2bf(s[g2][g][3]) };
        int pc = (2 * g + (fq >> 1)) ^ (fr & 7);
        *(short4v*)(Pw + g2 * 1024 + fr * 64 + pc * 8 + ((fq & 1) << 2)) = pk;
      }
      // rescale O (lane-local)
      #pragma unroll
      for (int c = 0; c < 4; ++c)
        #pragma unroll
        for (int jj = 0; jj < 4; ++jj) o[g2][c][jj] *= al;
    }

    // ---- O^T += V^T @ P^T : C[d][q]; V A-frags shared across groups ----
    bf16x8 pb[2][2];
    #pragma unroll
    for (int g2 = 0; g2 < 2; ++g2) {
      pb[g2][0] = *(const bf16x8*)(Pw + g2 * 1024 + fr * 64 + ((fq ^ (fr & 7)) << 3));
      pb[g2][1] = *(const bf16x8*)(Pw + g2 * 1024 + fr * 64 + (((4 + fq) ^ (fr & 7)) << 3));
    }
    #pragma unroll
    for (int c = 0; c < 4; ++c) {
      int d = 16 * c + fr;
      int sbase = (d & 7) ^ ((d >> 3) & 7);
      const short* vb = &Vt[cur][d * 64];
      bf16x8 va0 = *(const bf16x8*)(vb + ((fq ^ sbase) << 3));
      bf16x8 va1 = *(const bf16x8*)(vb + (((4 + fq) ^ sbase) << 3));
      #pragma unroll
      for (int g2 = 0; g2 < 2; ++g2) {
        o[g2][c] = __builtin_amdgcn_mfma_f32_16x16x32_bf16(va0, pb[g2][0], o[g2][c], 0, 0, 0);
        o[g2][c] = __builtin_amdgcn_mfma_f32_16x16x32_bf16(va1, pb[g2][1], o[g2][c], 0, 0, 0);
      }
    }

    if (t + 1 < nt) V_WRITE_(cur ^ 1);   // vmcnt wait lands after compute
    __syncthreads();                      // buf^1 ready; reads of cur done
    cur ^= 1;
  }

#undef V_LOAD_
#undef K_STAGE_
#undef V_WRITE_

  // ---- epilogue: O^T -> LDS (per-wave, swizzled) -> coalesced global ----
  int ql = lane >> 2, dc = lane & 3;
  int swz = ql & 7;
  #pragma unroll
  for (int g2 = 0; g2 < 2; ++g2) {
    float inv_l = 1.0f / l_r[g2];
    #pragma unroll
    for (int c = 0; c < 4; ++c) {
      short4v okk = { f2bf(o[g2][c][0] * inv_l), f2bf(o[g2][c][1] * inv_l),
                      f2bf(o[g2][c][2] * inv_l), f2bf(o[g2][c][3] * inv_l) };
      int pc = (2 * c + (fq >> 1)) ^ (fr & 7);
      *(short4v*)(Pw + g2 * 1024 + fr * 64 + pc * 8 + ((fq & 1) << 2)) = okk;
    }
    const short* ob = Pw + g2 * 1024 + ql * 64;
    bf16x8 r0 = *(const bf16x8*)(ob + (((2 * dc) ^ swz) << 3));
    bf16x8 r1 = *(const bf16x8*)(ob + (((2 * dc + 1) ^ swz) << 3));
    short* op = out + (size_t)(b * S_ + q0 + 32 * w + 16 * g2 + ql) * E_ + h * 64 + dc * 16;
    *(bf16x8*)op = r0;
    *(bf16x8*)(op + 8) = r1;
  }
}

// ---------------- launch ----------------
extern "C" void kernel_launch(void* const* d_in, const int* in_sizes, int n_in,
                              void* d_out, int out_size, void* d_ws, size_t ws_size,
                              hipStream_t stream) {
  const float* x      = (const float*)d_in[0];
  const float* ln1_w  = (const float*)d_in[1];
  const float* ln1_b  = (const float*)d_in[2];
  const float* qkv_w  = (const float*)d_in[3];
  const float* qkv_b  = (const float*)d_in[4];
  const float* proj_w = (const float*)d_in[5];
  const float* proj_b = (const float*)d_in[6];
  const float* ln2_w  = (const float*)d_in[7];
  const float* ln2_b  = (const float*)d_in[8];
  const float* fc1_w  = (const float*)d_in[9];
  const float* fc1_b  = (const float*)d_in[10];
  const float* fc2_w  = (const float*)d_in[11];
  const float* fc2_b  = (const float*)d_in[12];
  float* out = (float*)d_out;

  char* ws = (char*)d_ws;
  // Timeline-overlapped layout (80 MB total):
  short* xn1    = (short*)(ws + 0);              // 8 MB  (dead after qkv gemm)
  short* qkvb   = (short*)(ws + (8u  << 20));    // 24 MB (dead after attn)
  short* gelu_o = (short*)(ws + 0);              // 32 MB (reuses xn1+qkvb)
  short* attn_o = (short*)(ws + (32u << 20));    // 8 MB  (dead after proj gemm)
  short* h_ln2  = (short*)(ws + (32u << 20));    // 8 MB  (reuses attn_o)
  float* x_res  = (float*)(ws + (40u << 20));    // 16 MB fp32
  short* w_qkv  = (short*)(ws + (56u << 20));    // 6 MB
  short* w_proj = (short*)(ws + (62u << 20));    // 2 MB
  short* w_fc1  = (short*)(ws + (64u << 20));    // 8 MB
  short* w_fc2  = (short*)(ws + (72u << 20));    // 8 MB

  k_cvt4<<<dim3(4096, 4), 256, 0, stream>>>(qkv_w, w_qkv, 786432,
                                            proj_w, w_proj, 262144,
                                            fc1_w, w_fc1, 1048576,
                                            fc2_w, w_fc2, 1048576);

  k_ln<<<MROWS, 256, 0, stream>>>(x, ln1_w, ln1_b, xn1);
  k_gemm<0><<<dim3(24, 32), 256, 0, stream>>>(xn1, w_qkv, qkv_b, nullptr, qkvb,
                                              MROWS, TE_, E_);
  k_attn<<<dim3(S_ / 128, B_ * H_), 256, 0, stream>>>(qkvb, attn_o);
  k_gemm<1><<<dim3(8, 32), 256, 0, stream>>>(attn_o, w_proj, proj_b, x, x_res,
                                             MROWS, E_, E_);
  k_ln<<<MROWS, 256, 0, stream>>>(x_res, ln2_w, ln2_b, h_ln2);
  k_gemm<2><<<dim3(32, 32), 256, 0, stream>>>(h_ln2, w_fc1, fc1_b, nullptr, gelu_o,
                                              MROWS, 4096, E_);
  k_gemm<1><<<dim3(8, 32), 256, 0, stream>>>(gelu_o, w_fc2, fc2_b, x_res, out,
                                             MROWS, E_, 4096);
}

// Round 8
// 373.709 us; speedup vs baseline: 1.5162x; 1.0606x over previous
//
#include <hip/hip_runtime.h>
#include <hip/hip_bf16.h>

// Transformer block fwd: x:[2,2048,1024] fp32. bf16 MFMA GEMMs + flash attn.
// E=1024 H=16 D=64 HID=4096, causal, exact GELU, LN eps=1e-6.

#define E_    1024
#define TE_   3072
#define S_    2048
#define B_    2
#define H_    16
#define MROWS 4096   // B*S

typedef __attribute__((ext_vector_type(8))) short bf16x8;
typedef __attribute__((ext_vector_type(4))) short short4v;
typedef __attribute__((ext_vector_type(4))) float f32x4;

__device__ __forceinline__ short f2bf(float f) {
  union { float f; unsigned u; } v; v.f = f;
  unsigned r = v.u + 0x7fffu + ((v.u >> 16) & 1u);  // RNE
  return (short)(r >> 16);
}
__device__ __forceinline__ float bf2f(short s) {
  union { unsigned u; float f; } v; v.u = ((unsigned)(unsigned short)s) << 16;
  return v.f;
}
__device__ __forceinline__ void gload_lds16(const void* g, void* l) {
  __builtin_amdgcn_global_load_lds(
      (const __attribute__((address_space(1))) unsigned int*)g,
      (__attribute__((address_space(3))) unsigned int*)l, 16, 0, 0);
}
__device__ __forceinline__ float exp2_fast(float x) {  // exact v_exp_f32 (2^x)
  float r; asm("v_exp_f32 %0, %1" : "=v"(r) : "v"(x)); return r;
}
__device__ __forceinline__ float gelu_f(float v) {
  return 0.5f * v * (1.0f + erff(v * 0.70710678118654752f));
}

// ---------------- fp32 -> bf16 weight convert (4 tensors fused) -----------
__global__ __launch_bounds__(256) void k_cvt4(const float* __restrict__ i0, short* __restrict__ o0, int n0,
                                              const float* __restrict__ i1, short* __restrict__ o1, int n1,
                                              const float* __restrict__ i2, short* __restrict__ o2, int n2,
                                              const float* __restrict__ i3, short* __restrict__ o3, int n3) {
  const float* in; short* out; int n;
  switch (blockIdx.y) {
    case 0: in = i0; out = o0; n = n0; break;
    case 1: in = i1; out = o1; n = n1; break;
    case 2: in = i2; out = o2; n = n2; break;
    default: in = i3; out = o3; n = n3; break;
  }
  int i = blockIdx.x * 256 + threadIdx.x;
  if (i >= n) return;
  float4 v = ((const float4*)in)[i];
  short4v o = { f2bf(v.x), f2bf(v.y), f2bf(v.z), f2bf(v.w) };
  ((short4v*)out)[i] = o;
}

// ---------------- LayerNorm fp32 -> bf16 ----------------
__global__ __launch_bounds__(256) void k_ln(const float* __restrict__ x,
                                            const float* __restrict__ w,
                                            const float* __restrict__ b,
                                            short* __restrict__ out) {
  int row = blockIdx.x;
  int tid = threadIdx.x;
  float4 v = ((const float4*)(x + (size_t)row * E_))[tid];
  float s  = v.x + v.y + v.z + v.w;
  float s2 = v.x*v.x + v.y*v.y + v.z*v.z + v.w*v.w;
  #pragma unroll
  for (int d = 1; d < 64; d <<= 1) { s += __shfl_xor(s, d); s2 += __shfl_xor(s2, d); }
  __shared__ float rs[4], rq[4];
  int wv = tid >> 6;
  if ((tid & 63) == 0) { rs[wv] = s; rq[wv] = s2; }
  __syncthreads();
  s  = rs[0] + rs[1] + rs[2] + rs[3];
  s2 = rq[0] + rq[1] + rq[2] + rq[3];
  float mu  = s * (1.0f / E_);
  float var = fmaxf(s2 * (1.0f / E_) - mu * mu, 0.0f);
  float inv = rsqrtf(var + 1e-6f);
  float4 wv4 = ((const float4*)w)[tid];
  float4 bv4 = ((const float4*)b)[tid];
  short4v o = { f2bf((v.x - mu) * inv * wv4.x + bv4.x),
                f2bf((v.y - mu) * inv * wv4.y + bv4.y),
                f2bf((v.z - mu) * inv * wv4.z + bv4.z),
                f2bf((v.w - mu) * inv * wv4.w + bv4.w) };
  ((short4v*)(out + (size_t)row * E_))[tid] = o;
}

// ---------------- bf16 GEMM: out[m,n] = sum_k A[m,k]*W[n,k] (+epilogue) ----
// 512 threads (8 waves 2Mx4N), BM=BN=128, BK=64. Depth-2 counted-vmcnt
// pipeline (T3/T4): prologue stages tiles 0,1; each iter waits vmcnt(4)
// (tile t landed, t+1 in flight), computes, then stages t+2 into the
// just-consumed buffer after an lgkm-drained barrier. LDS chunk-XOR
// swizzle (chunk ^= row&7) applied both-sides (pre-swizzled global src).
// EPI: 0 = +bias -> bf16 ; 1 = +bias+res -> fp32 ; 2 = +bias, gelu -> bf16
template <int EPI>
__global__ __launch_bounds__(512, 2) void k_gemm(const short* __restrict__ A,
                                                 const short* __restrict__ W,
                                                 const float* __restrict__ bias,
                                                 const float* __restrict__ res,
                                                 void* __restrict__ outv,
                                                 int M, int N, int K) {
  __shared__ short As[2][8192];   // [128 rows][64 k] bf16, swizzled
  __shared__ short Ws[2][8192];
  int tid  = threadIdx.x;
  int lane = tid & 63, wave = tid >> 6;
  int wm = wave >> 2, wn = wave & 3;       // 2 x 4 wave grid
  // XCD-aware bijective block swizzle (all grids have nwg % 8 == 0)
  int nwg = (int)(gridDim.x * gridDim.y);
  int id  = (int)(blockIdx.y * gridDim.x + blockIdx.x);
  int qc  = nwg >> 3;
  int sid = (id & 7) * qc + (id >> 3);
  int bx = sid % (int)gridDim.x, by = sid / (int)gridDim.x;
  int m0 = by * 128, n0 = bx * 128;
  int fr = lane & 15, fq = lane >> 4;      // frag row / k-group
  int fp = fr & 7;                          // row parity for swizzle

  f32x4 acc[4][2];
  #pragma unroll
  for (int i = 0; i < 4; ++i)
    #pragma unroll
    for (int j = 0; j < 2; ++j) acc[i][j] = (f32x4){0.f, 0.f, 0.f, 0.f};

  int srow = tid >> 3;                      // staging row 0..63 (+64 2nd call)
  int swz  = ((tid & 7) ^ (srow & 7)) << 3; // pre-swizzled source chunk
  const short* Asrc = A + (size_t)(m0 + srow) * K + swz;
  const short* Wsrc = W + (size_t)(n0 + srow) * K + swz;
  size_t l64K = (size_t)64 * K;

#define STAGE_(buf, k0)                                      \
  do {                                                       \
    gload_lds16(Asrc + (k0),        &As[buf][tid * 8]);      \
    gload_lds16(Asrc + l64K + (k0), &As[buf][4096 + tid * 8]); \
    gload_lds16(Wsrc + (k0),        &Ws[buf][tid * 8]);      \
    gload_lds16(Wsrc + l64K + (k0), &Ws[buf][4096 + tid * 8]); \
  } while (0)

#define COMPUTE_(bb)                                                          \
  do {                                                                        \
    bf16x8 af[4][2], bfr[2][2];                                               \
    _Pragma("unroll")                                                         \
    for (int mi = 0; mi < 4; ++mi)                                            \
      _Pragma("unroll")                                                       \
      for (int kk = 0; kk < 2; ++kk)                                          \
        af[mi][kk] = *(const bf16x8*)(&As[bb][(wm * 64 + mi * 16 + fr) * 64 + \
                                              (((kk << 2) + fq) ^ fp) * 8]);  \
    _Pragma("unroll")                                                         \
    for (int ni = 0; ni < 2; ++ni)                                            \
      _Pragma("unroll")                                                       \
      for (int kk = 0; kk < 2; ++kk)                                          \
        bfr[ni][kk] = *(const bf16x8*)(&Ws[bb][(wn * 32 + ni * 16 + fr) * 64 + \
                                               (((kk << 2) + fq) ^ fp) * 8]); \
    __builtin_amdgcn_s_setprio(1);                                            \
    _Pragma("unroll")                                                         \
    for (int mi = 0; mi < 4; ++mi)                                            \
      _Pragma("unroll")                                                       \
      for (int ni = 0; ni < 2; ++ni)                                          \
        _Pragma("unroll")                                                     \
        for (int kk = 0; kk < 2; ++kk)                                        \
          acc[mi][ni] = __builtin_amdgcn_mfma_f32_16x16x32_bf16(              \
              af[mi][kk], bfr[ni][kk], acc[mi][ni], 0, 0, 0);                 \
    __builtin_amdgcn_s_setprio(0);                                            \
  } while (0)

  int nt = K >> 6;
  STAGE_(0, 0);
  STAGE_(1, 64);
  int cur = 0;
  for (int t = 0; t < nt - 1; ++t) {
    asm volatile("s_waitcnt vmcnt(4)" ::: "memory");  // tile t landed; t+1 in flight
    __builtin_amdgcn_s_barrier();
    COMPUTE_(cur);
    asm volatile("s_waitcnt lgkmcnt(0)" ::: "memory"); // reads of cur done
    __builtin_amdgcn_s_barrier();
    if (t < nt - 2) STAGE_(cur, (size_t)(t + 2) * 64);
    cur ^= 1;
  }
  asm volatile("s_waitcnt vmcnt(0)" ::: "memory");
  __builtin_amdgcn_s_barrier();
  COMPUTE_(cur);

#undef STAGE_
#undef COMPUTE_

  #pragma unroll
  for (int mi = 0; mi < 4; ++mi) {
    #pragma unroll
    for (int ni = 0; ni < 2; ++ni) {
      int gm0 = m0 + wm * 64 + mi * 16 + fq * 4;
      int gn  = n0 + wn * 32 + ni * 16 + fr;
      float bv = bias[gn];
      #pragma unroll
      for (int j = 0; j < 4; ++j) {
        size_t idx = (size_t)(gm0 + j) * N + gn;
        float v = acc[mi][ni][j] + bv;
        if (EPI == 0)      ((short*)outv)[idx] = f2bf(v);
        else if (EPI == 1) ((float*)outv)[idx] = v + res[idx];
        else               ((short*)outv)[idx] = f2bf(gelu_f(v));
      }
    }
  }
}

// ---------------- causal flash attention (swapped-operand) ----------------
// QBLK=128 (4 waves x 32 q-rows as 2 fragment-groups), KVBLK=64,
// double-buffered K/V with prefetch: issue loads for tile t+1 before
// compute(t), V-reg->LDS write after compute, ONE barrier per tile.
// Swapped QK^T/PV: lane owns one q-row -> lane-local softmax/rescale.
__global__ __launch_bounds__(256, 3) void k_attn(const short* __restrict__ qkv,
                                                 short* __restrict__ out) {
  __shared__ short Kt[2][64 * 64];   // [key][d] swizzled via global src
  __shared__ short Vt[2][64 * 64];   // V^T [d][key] swizzled
  __shared__ short Pl[4][2048];      // per-wave P (2 q-groups), reused for O
  int tid  = threadIdx.x;
  int lane = tid & 63, w = tid >> 6;
  int qb   = (int)gridDim.x - 1 - (int)blockIdx.x;   // heavy blocks first
  int q0   = qb * 128;
  int bh   = blockIdx.y;
  int b    = bh >> 4, h = bh & 15;
  int fr   = lane & 15, fq = lane >> 4, fk = fq * 8;
  const float sc = 0.18033688011112042f;   // 0.125 * log2(e) (exp2 domain)

  // Q fragments: group g2 covers q-rows q0+w*32+g2*16+fr
  bf16x8 qa[2][2];
  #pragma unroll
  for (int g2 = 0; g2 < 2; ++g2) {
    const short* qp = qkv + (size_t)(b * S_ + q0 + w * 32 + g2 * 16 + fr) * TE_ + h * 64;
    qa[g2][0] = *(const bf16x8*)(qp + fk);
    qa[g2][1] = *(const bf16x8*)(qp + 32 + fk);
  }

  float m_r[2] = {-__builtin_inff(), -__builtin_inff()};
  float l_r[2] = {0.f, 0.f};
  f32x4 o[2][4];
  #pragma unroll
  for (int g2 = 0; g2 < 2; ++g2)
    #pragma unroll
    for (int c = 0; c < 4; ++c) o[g2][c] = (f32x4){0.f, 0.f, 0.f, 0.f};

  int srow = tid >> 3;      // staging row 0..31 (+32 on round 1)
  int schunk = tid & 7;     // 16B chunk within 128B row
  short* Pw = &Pl[w][0];
  bf16x8 vv[2];

#define V_LOAD_(kvv)                                                          \
  do {                                                                        \
    _Pragma("unroll")                                                         \
    for (int r = 0; r < 2; ++r) {                                             \
      size_t grow = (size_t)(b * S_ + (kvv) + srow + 32 * r) * TE_ + h * 64;  \
      vv[r] = *(const bf16x8*)(qkv + grow + 2 * E_ + (schunk << 3));          \
    }                                                                         \
  } while (0)

#define K_STAGE_(buf, kvv)                                                    \
  do {                                                                        \
    _Pragma("unroll")                                                         \
    for (int r = 0; r < 2; ++r) {                                             \
      size_t grow = (size_t)(b * S_ + (kvv) + srow + 32 * r) * TE_ + h * 64;  \
      gload_lds16(qkv + grow + E_ + ((schunk ^ (srow & 7)) << 3),             \
                  &Kt[buf][r * 2048 + tid * 8]);                              \
    }                                                                         \
  } while (0)

#define V_WRITE_(buf)                                                         \
  do {                                                                        \
    _Pragma("unroll")                                                         \
    for (int r = 0; r < 2; ++r) {                                             \
      int row = srow + 32 * r;                                                \
      int kc = row >> 3, kwi = row & 7;                                       \
      _Pragma("unroll")                                                       \
      for (int j = 0; j < 8; ++j) {                                           \
        int d = (schunk << 3) + j;                                            \
        int csw = kc ^ (d & 7) ^ ((d >> 3) & 7);                              \
        Vt[buf][d * 64 + csw * 8 + kwi] = vv[r][j];                           \
      }                                                                       \
    }                                                                         \
  } while (0)

  // prologue: stage tile 0 into buf 0
  V_LOAD_(0);
  K_STAGE_(0, 0);
  V_WRITE_(0);
  __syncthreads();
  int cur = 0;
  int nt = 2 * qb + 2;

  for (int t = 0; t < nt; ++t) {
    int kv = t * 64;
    if (t + 1 < nt) {             // prefetch next tile (in flight over compute)
      V_LOAD_((t + 1) * 64);
      K_STAGE_(cur ^ 1, (t + 1) * 64);
    }

    // ---- K A-frags (shared by both q-groups) ----
    int sw = fr & 7;
    bf16x8 ka[4][2];
    #pragma unroll
    for (int g = 0; g < 4; ++g) {
      const short* kb = &Kt[cur][((g << 4) + fr) * 64];
      ka[g][0] = *(const bf16x8*)(kb + ((fq ^ sw) << 3));
      ka[g][1] = *(const bf16x8*)(kb + (((4 + fq) ^ sw) << 3));
    }
    // ---- S^T = K @ Q^T : lane owns q=fr (per group), keys 16g+4fq+jj ----
    f32x4 s[2][4];
    #pragma unroll
    for (int g2 = 0; g2 < 2; ++g2)
      #pragma unroll
      for (int g = 0; g < 4; ++g) {
        f32x4 t0 = (f32x4){0.f, 0.f, 0.f, 0.f};
        t0 = __builtin_amdgcn_mfma_f32_16x16x32_bf16(ka[g][0], qa[g2][0], t0, 0, 0, 0);
        t0 = __builtin_amdgcn_mfma_f32_16x16x32_bf16(ka[g][1], qa[g2][1], t0, 0, 0, 0);
        s[g2][g] = t0;
      }
    #pragma unroll
    for (int g2 = 0; g2 < 2; ++g2)
      #pragma unroll
      for (int g = 0; g < 4; ++g)
        #pragma unroll
        for (int jj = 0; jj < 4; ++jj) s[g2][g][jj] *= sc;

    if (kv + 64 > q0) {            // diagonal region (block-uniform test)
      #pragma unroll
      for (int g2 = 0; g2 < 2; ++g2) {
        int qr = (q0 - kv) + 32 * w + 16 * g2 + fr;
        #pragma unroll
        for (int g = 0; g < 4; ++g)
          #pragma unroll
          for (int jj = 0; jj < 4; ++jj)
            if (16 * g + 4 * fq + jj > qr) s[g2][g][jj] = -__builtin_inff();
      }
    }

    // ---- online softmax per q-group: in-lane tree + 2 shfl ----
    #pragma unroll
    for (int g2 = 0; g2 < 2; ++g2) {
      float mg0 = fmaxf(fmaxf(s[g2][0][0], s[g2][0][1]), fmaxf(s[g2][0][2], s[g2][0][3]));
      float mg1 = fmaxf(fmaxf(s[g2][1][0], s[g2][1][1]), fmaxf(s[g2][1][2], s[g2][1][3]));
      float mg2 = fmaxf(fmaxf(s[g2][2][0], s[g2][2][1]), fmaxf(s[g2][2][2], s[g2][2][3]));
      float mg3 = fmaxf(fmaxf(s[g2][3][0], s[g2][3][1]), fmaxf(s[g2][3][2], s[g2][3][3]));
      float mt = fmaxf(fmaxf(mg0, mg1), fmaxf(mg2, mg3));
      mt = fmaxf(mt, __shfl_xor(mt, 16));
      mt = fmaxf(mt, __shfl_xor(mt, 32));
      float mn = fmaxf(m_r[g2], mt);
      float al = exp2_fast(m_r[g2] - mn);
      m_r[g2] = mn;
      #pragma unroll
      for (int g = 0; g < 4; ++g)
        #pragma unroll
        for (int jj = 0; jj < 4; ++jj) s[g2][g][jj] = exp2_fast(s[g2][g][jj] - mn);
      f32x4 s4 = s[g2][0] + s[g2][1] + s[g2][2] + s[g2][3];
      float ps = (s4[0] + s4[1]) + (s4[2] + s4[3]);
      ps += __shfl_xor(ps, 16);
      ps += __shfl_xor(ps, 32);
      l_r[g2] = l_r[g2] * al + ps;

      // P -> per-wave LDS (bf16, swizzled b64 stores)
      #pragma unroll
      for (int g = 0; g < 4; ++g) {
        short4v pk = { f2bf(s[g2][g][0]), f2bf(s[g2][g][1]),
                       f2bf(s[g2][g][2]), f2bf(s[g2][g][3]) };
        int pc = (2 * g + (fq >> 1)) ^ (fr & 7);
        *(short4v*)(Pw + g2 * 1024 + fr * 64 + pc * 8 + ((fq & 1) << 2)) = pk;
      }
      // rescale O (lane-local)
      #pragma unroll
      for (int c = 0; c < 4; ++c)
        #pragma unroll
        for (int jj = 0; jj < 4; ++jj) o[g2][c][jj] *= al;
    }

    // ---- O^T += V^T @ P^T : C[d][q]; V A-frags shared across groups ----
    bf16x8 pb[2][2];
    #pragma unroll
    for (int g2 = 0; g2 < 2; ++g2) {
      pb[g2][0] = *(const bf16x8*)(Pw + g2 * 1024 + fr * 64 + ((fq ^ (fr & 7)) << 3));
      pb[g2][1] = *(const bf16x8*)(Pw + g2 * 1024 + fr * 64 + (((4 + fq) ^ (fr & 7)) << 3));
    }
    #pragma unroll
    for (int c = 0; c < 4; ++c) {
      int d = 16 * c + fr;
      int sbase = (d & 7) ^ ((d >> 3) & 7);
      const short* vb = &Vt[cur][d * 64];
      bf16x8 va0 = *(const bf16x8*)(vb + ((fq ^ sbase) << 3));
      bf16x8 va1 = *(const bf16x8*)(vb + (((4 + fq) ^ sbase) << 3));
      #pragma unroll
      for (int g2 = 0; g2 < 2; ++g2) {
        o[g2][c] = __builtin_amdgcn_mfma_f32_16x16x32_bf16(va0, pb[g2][0], o[g2][c], 0, 0, 0);
        o[g2][c] = __builtin_amdgcn_mfma_f32_16x16x32_bf16(va1, pb[g2][1], o[g2][c], 0, 0, 0);
      }
    }

    if (t + 1 < nt) V_WRITE_(cur ^ 1);   // vmcnt wait lands after compute
    __syncthreads();                      // buf^1 ready; reads of cur done
    cur ^= 1;
  }

#undef V_LOAD_
#undef K_STAGE_
#undef V_WRITE_

  // ---- epilogue: O^T -> LDS (per-wave, swizzled) -> coalesced global ----
  int ql = lane >> 2, dc = lane & 3;
  int swz = ql & 7;
  #pragma unroll
  for (int g2 = 0; g2 < 2; ++g2) {
    float inv_l = 1.0f / l_r[g2];
    #pragma unroll
    for (int c = 0; c < 4; ++c) {
      short4v okk = { f2bf(o[g2][c][0] * inv_l), f2bf(o[g2][c][1] * inv_l),
                      f2bf(o[g2][c][2] * inv_l), f2bf(o[g2][c][3] * inv_l) };
      int pc = (2 * c + (fq >> 1)) ^ (fr & 7);
      *(short4v*)(Pw + g2 * 1024 + fr * 64 + pc * 8 + ((fq & 1) << 2)) = okk;
    }
    const short* ob = Pw + g2 * 1024 + ql * 64;
    bf16x8 r0 = *(const bf16x8*)(ob + (((2 * dc) ^ swz) << 3));
    bf16x8 r1 = *(const bf16x8*)(ob + (((2 * dc + 1) ^ swz) << 3));
    short* op = out + (size_t)(b * S_ + q0 + 32 * w + 16 * g2 + ql) * E_ + h * 64 + dc * 16;
    *(bf16x8*)op = r0;
    *(bf16x8*)(op + 8) = r1;
  }
}

// ---------------- launch ----------------
extern "C" void kernel_launch(void* const* d_in, const int* in_sizes, int n_in,
                              void* d_out, int out_size, void* d_ws, size_t ws_size,
                              hipStream_t stream) {
  const float* x      = (const float*)d_in[0];
  const float* ln1_w  = (const float*)d_in[1];
  const float* ln1_b  = (const float*)d_in[2];
  const float* qkv_w  = (const float*)d_in[3];
  const float* qkv_b  = (const float*)d_in[4];
  const float* proj_w = (const float*)d_in[5];
  const float* proj_b = (const float*)d_in[6];
  const float* ln2_w  = (const float*)d_in[7];
  const float* ln2_b  = (const float*)d_in[8];
  const float* fc1_w  = (const float*)d_in[9];
  const float* fc1_b  = (const float*)d_in[10];
  const float* fc2_w  = (const float*)d_in[11];
  const float* fc2_b  = (const float*)d_in[12];
  float* out = (float*)d_out;

  char* ws = (char*)d_ws;
  // Timeline-overlapped layout (80 MB total):
  short* xn1    = (short*)(ws + 0);              // 8 MB  (dead after qkv gemm)
  short* qkvb   = (short*)(ws + (8u  << 20));    // 24 MB (dead after attn)
  short* gelu_o = (short*)(ws + 0);              // 32 MB (reuses xn1+qkvb)
  short* attn_o = (short*)(ws + (32u << 20));    // 8 MB  (dead after proj gemm)
  short* h_ln2  = (short*)(ws + (32u << 20));    // 8 MB  (reuses attn_o)
  float* x_res  = (float*)(ws + (40u << 20));    // 16 MB fp32
  short* w_qkv  = (short*)(ws + (56u << 20));    // 6 MB
  short* w_proj = (short*)(ws + (62u << 20));    // 2 MB
  short* w_fc1  = (short*)(ws + (64u << 20));    // 8 MB
  short* w_fc2  = (short*)(ws + (72u << 20));    // 8 MB

  k_cvt4<<<dim3(4096, 4), 256, 0, stream>>>(qkv_w, w_qkv, 786432,
                                            proj_w, w_proj, 262144,
                                            fc1_w, w_fc1, 1048576,
                                            fc2_w, w_fc2, 1048576);

  k_ln<<<MROWS, 256, 0, stream>>>(x, ln1_w, ln1_b, xn1);
  k_gemm<0><<<dim3(24, 32), 512, 0, stream>>>(xn1, w_qkv, qkv_b, nullptr, qkvb,
                                              MROWS, TE_, E_);
  k_attn<<<dim3(S_ / 128, B_ * H_), 256, 0, stream>>>(qkvb, attn_o);
  k_gemm<1><<<dim3(8, 32), 512, 0, stream>>>(attn_o, w_proj, proj_b, x, x_res,
                                             MROWS, E_, E_);
  k_ln<<<MROWS, 256, 0, stream>>>(x_res, ln2_w, ln2_b, h_ln2);
  k_gemm<2><<<dim3(32, 32), 512, 0, stream>>>(h_ln2, w_fc1, fc1_b, nullptr, gelu_o,
                                              MROWS, 4096, E_);
  k_gemm<1><<<dim3(8, 32), 512, 0, stream>>>(gelu_o, w_fc2, fc2_b, x_res, out,
                                             MROWS, E_, 4096);
}